// Round 9
// baseline (273.288 us; speedup 1.0000x reference)
//
#include <hip/hip_runtime.h>
#include <hip/hip_bf16.h>
#include <math.h>

#define BB 2
#define LL 2048
#define DM 1024
#define DS 16
#define DI 2048
#define KX 33          // 1 + 2*D_STATE
#define D2 (2*DI)      // 4096
#define NC 64          // scan chunks
#define LC 32          // chunk length (NC*LC == LL)
#define SEGS 32        // xproj d-segments
#define SEGW 64        // d per segment

typedef __attribute__((ext_vector_type(8))) short short8v;   // 8 bf16 (4 VGPRs)
typedef __attribute__((ext_vector_type(4))) float f32x4;

__device__ __forceinline__ void gload16(const void* g, void* l) {
    __builtin_amdgcn_global_load_lds((const __attribute__((address_space(1))) void*)g,
                                     (__attribute__((address_space(3))) void*)l,
                                     16, 0, 0);
}

__device__ __forceinline__ ushort tobf(float v) {
    __hip_bfloat16 h = __float2bfloat16(v);
    return *(ushort*)&h;
}
__device__ __forceinline__ float bf2f(ushort u) {
    return __uint_as_float((unsigned)u << 16);
}

// ---------------------------------------------------------------------------
// merged fp32 -> bf16 conversion for Win (first na8*8 elems) then hs,
// writing one contiguous bf16 region (Winb | hsb).
// ---------------------------------------------------------------------------
__global__ __launch_bounds__(256) void cvt2_k(const float* __restrict__ a,
                                              const float* __restrict__ b,
                                              int na8, int ntot8,
                                              ushort* __restrict__ o) {
    int i = blockIdx.x * 256 + threadIdx.x;
    if (i >= ntot8) return;
    const float* src = (i < na8) ? &a[(size_t)i * 8] : &b[(size_t)(i - na8) * 8];
    float4 v0 = *(const float4*)&src[0];
    float4 v1 = *(const float4*)&src[4];
    float v[8] = {v0.x, v0.y, v0.z, v0.w, v1.x, v1.y, v1.z, v1.w};
    ushort u[8];
    #pragma unroll
    for (int j = 0; j < 8; j++) u[j] = tobf(v[j]);
    *(ushort4*)&o[(size_t)i * 8]     = make_ushort4(u[0], u[1], u[2], u[3]);
    *(ushort4*)&o[(size_t)i * 8 + 4] = make_ushort4(u[4], u[5], u[6], u[7]);
}

__global__ __launch_bounds__(256) void cvt_bf16_k(const float* __restrict__ in,
                                                  ushort* __restrict__ o, int n8) {
    int i = blockIdx.x * 256 + threadIdx.x;
    if (i >= n8) return;
    float4 a = *(const float4*)&in[(size_t)i * 8];
    float4 b = *(const float4*)&in[(size_t)i * 8 + 4];
    float v[8] = {a.x, a.y, a.z, a.w, b.x, b.y, b.z, b.w};
    ushort u[8];
    #pragma unroll
    for (int j = 0; j < 8; j++) u[j] = tobf(v[j]);
    *(ushort4*)&o[(size_t)i * 8]     = make_ushort4(u[0], u[1], u[2], u[3]);
    *(ushort4*)&o[(size_t)i * 8 + 4] = make_ushort4(u[4], u[5], u[6], u[7]);
}

// ---------------------------------------------------------------------------
// NT bf16 MFMA GEMM (m97 structure), 128x128 tile, 4 waves, 4x4 fragments.
// MODE 0: C bf16, row=d, col=bl -> xzb[((col>>11)*D2 + row)*LL + (col&2047)]
// MODE 1: C fp32, row=bl, col=m -> out[row*DM + col]
// ---------------------------------------------------------------------------
template<int K, int MODE>
__global__ __launch_bounds__(256) void mfma_nt_k(const ushort* __restrict__ A,
                                                 const ushort* __restrict__ Bm,
                                                 void* __restrict__ Cout) {
    __shared__ ushort Als[128][32];
    __shared__ ushort Bls[128][32];
    const int n0 = blockIdx.x * 128;
    const int m0 = blockIdx.y * 128;
    const int tid = threadIdx.x;
    const int w = tid >> 6, lane = tid & 63;
    const int wr = (w >> 1) * 64, wc = (w & 1) * 64;
    const int lrow = lane & 15;
    const int kq = lane >> 4;

    const int srow = (lane >> 2);
    const int skof = (lane & 3) * 8;

    f32x4 acc[4][4] = {};
    for (int k0 = 0; k0 < K; k0 += 32) {
        #pragma unroll
        for (int j = 0; j < 2; j++) {
            const int rbase = w * 32 + j * 16;
            gload16(&A [(size_t)(m0 + rbase + srow) * K + k0 + skof], &Als[rbase][0]);
            gload16(&Bm[(size_t)(n0 + rbase + srow) * K + k0 + skof], &Bls[rbase][0]);
        }
        __syncthreads();
        short8v af[4], bf[4];
        #pragma unroll
        for (int i = 0; i < 4; i++) {
            af[i] = *(const short8v*)&Als[wr + i * 16 + lrow][kq * 8];
            bf[i] = *(const short8v*)&Bls[wc + i * 16 + lrow][kq * 8];
        }
        #pragma unroll
        for (int i = 0; i < 4; i++)
            #pragma unroll
            for (int jn = 0; jn < 4; jn++)
                acc[i][jn] = __builtin_amdgcn_mfma_f32_16x16x32_bf16(af[i], bf[jn], acc[i][jn], 0, 0, 0);
        __syncthreads();
    }
    #pragma unroll
    for (int i = 0; i < 4; i++) {
        #pragma unroll
        for (int jn = 0; jn < 4; jn++) {
            #pragma unroll
            for (int r = 0; r < 4; r++) {
                int row = m0 + wr + i * 16 + (lane >> 4) * 4 + r;
                int col = n0 + wc + jn * 16 + (lane & 15);
                if constexpr (MODE == 0) {
                    size_t off = ((size_t)(col >> 11) * D2 + row) * LL + (col & (LL - 1));
                    ((ushort*)Cout)[off] = tobf(acc[i][jn][r]);
                } else {
                    ((float*)Cout)[(size_t)row * DM + col] = acc[i][jn][r];
                }
            }
        }
    }
}

// ---------------------------------------------------------------------------
// Depthwise causal conv(4) + bias + SiLU on bf16 x-half of xzb -> xc (fp32)
// ---------------------------------------------------------------------------
__global__ __launch_bounds__(256) void conv_silu_k(const ushort* __restrict__ xzb,
                                                   const float* __restrict__ cw,
                                                   const float* __restrict__ cb,
                                                   float* __restrict__ xc) {
    const int row = blockIdx.x;             // 0..B*DI-1
    const int b = row >> 11, d = row & (DI - 1);
    const ushort* xr = xzb + ((size_t)b * D2 + d) * LL;
    float4 wv = *(const float4*)&cw[d * 4];
    const float w0 = wv.x, w1 = wv.y, w2 = wv.z, w3 = wv.w;
    const float bias = cb[d];
    const int l0 = threadIdx.x * 8;
    ushort4 pv = (l0 >= 4) ? *(const ushort4*)&xr[l0 - 4]
                           : make_ushort4(0, 0, 0, 0);
    ushort4 c0 = *(const ushort4*)&xr[l0];
    ushort4 c1 = *(const ushort4*)&xr[l0 + 4];
    float buf[11] = {bf2f(pv.y), bf2f(pv.z), bf2f(pv.w),
                     bf2f(c0.x), bf2f(c0.y), bf2f(c0.z), bf2f(c0.w),
                     bf2f(c1.x), bf2f(c1.y), bf2f(c1.z), bf2f(c1.w)};
    float o[8];
    #pragma unroll
    for (int j = 0; j < 8; j++) {
        float s = fmaf(buf[j], w0, fmaf(buf[j + 1], w1,
                  fmaf(buf[j + 2], w2, fmaf(buf[j + 3], w3, bias))));
        o[j] = s / (1.f + __expf(-s));
    }
    float* out = xc + ((size_t)b * DI + d) * LL + l0;
    *(float4*)&out[0] = make_float4(o[0], o[1], o[2], o[3]);
    *(float4*)&out[4] = make_float4(o[4], o[5], o[6], o[7]);
}

// ---------------------------------------------------------------------------
// x_dbl partials: part[seg][b][k][l] = sum_{d in seg(64)} xc[b][d][l]*Wx[k][d]
// ---------------------------------------------------------------------------
__global__ __launch_bounds__(256) void xproj_partial_k(const float* __restrict__ xc,
                                                       const float* __restrict__ Wx,
                                                       float* __restrict__ part) {
    const int lt = blockIdx.x;             // 0..7  (512 l each)
    const int seg = blockIdx.y;            // 0..31 (64 d each)
    const int tid = threadIdx.x;
    const int bl0 = lt * 512;
    const int b = bl0 >> 11;
    const int l = (bl0 & (LL - 1)) + tid * 2;
    const int dbase = seg * SEGW;

    __shared__ float w[SEGW][36];          // [dd][kk], row padded to 36
    for (int kk = tid >> 6; kk < KX; kk += 4)
        w[tid & 63][kk] = Wx[(size_t)kk * DI + dbase + (tid & 63)];
    __syncthreads();

    float2 acc[KX];
    #pragma unroll
    for (int kk = 0; kk < KX; kk++) acc[kk] = make_float2(0.f, 0.f);

    const float* xb = xc + ((size_t)b * DI + dbase) * LL + l;
    #pragma unroll 4
    for (int dd = 0; dd < SEGW; dd++) {
        float2 xv = *(const float2*)&xb[(size_t)dd * LL];
        #pragma unroll
        for (int q = 0; q < 8; q++) {
            float4 wv = *(const float4*)&w[dd][q * 4];
            float wa[4] = {wv.x, wv.y, wv.z, wv.w};
            #pragma unroll
            for (int t = 0; t < 4; t++) {
                acc[q * 4 + t].x = fmaf(xv.x, wa[t], acc[q * 4 + t].x);
                acc[q * 4 + t].y = fmaf(xv.y, wa[t], acc[q * 4 + t].y);
            }
        }
        float wl = w[dd][32];
        acc[32].x = fmaf(xv.x, wl, acc[32].x);
        acc[32].y = fmaf(xv.y, wl, acc[32].y);
    }
    #pragma unroll
    for (int kk = 0; kk < KX; kk++)
        *(float2*)&part[(((size_t)seg * BB + b) * KX + kk) * LL + l] = acc[kk];
}

__global__ __launch_bounds__(256) void xproj_reduce_k(const float* __restrict__ part,
                                                      float* __restrict__ xdbl) {
    const int i = blockIdx.x * 256 + threadIdx.x;    // float4 index
    if (i >= (BB * KX * LL) / 4) return;
    float4 s = make_float4(0.f, 0.f, 0.f, 0.f);
    #pragma unroll
    for (int seg = 0; seg < SEGS; seg++) {
        float4 v = *(const float4*)&part[(size_t)seg * BB * KX * LL + (size_t)i * 4];
        s.x += v.x; s.y += v.y; s.z += v.z; s.w += v.w;
    }
    *(float4*)&xdbl[(size_t)i * 4] = s;
}

// ---------------------------------------------------------------------------
// scanA: h-only local chunk scan (h_in = 0). No C reads, no y, no cum.
// Writes terminal h -> hloc, chunk dt-sum -> sumc. Thread-per-d.
// ---------------------------------------------------------------------------
__global__ __launch_bounds__(256) void scanA_k(const float* __restrict__ xc,
                                               const float* __restrict__ xdbl,
                                               const float* __restrict__ Alog,
                                               const float* __restrict__ Wdt,
                                               const float* __restrict__ bdt,
                                               float* __restrict__ hloc,
                                               float* __restrict__ sumc) {
    const int blk = blockIdx.x;            // c*16 + b*8 + dblk
    const int dblk = blk & 7;
    const int b = (blk >> 3) & 1;
    const int c = blk >> 4;
    const int tid = threadIdx.x;
    const int d = dblk * 256 + tid;

    __shared__ float Bt[LC][16], sdtr[LC];

    float a2[16], h[16];
    #pragma unroll
    for (int n = 0; n < 16; n++) {
        a2[n] = -expf(Alog[(size_t)d * DS + n]) * 1.44269504f;
        h[n] = 0.f;
    }
    const float wdt = Wdt[d], bdtv = bdt[d];

    #pragma unroll
    for (int i = tid; i < LC * 16; i += 256) {
        int n = i >> 5, l = i & 31;
        Bt[l][n] = xdbl[((size_t)b * KX + 1 + n) * LL + c * LC + l];
    }
    if (tid < LC) sdtr[tid] = xdbl[(size_t)b * KX * LL + c * LC + tid];
    __syncthreads();

    float cum = 0.f;
    const float* xrow = xc + ((size_t)b * DI + d) * LL + c * LC;

    for (int g = 0; g < LC; g += 16) {
        float4 x0 = *(const float4*)&xrow[g];
        float4 x1 = *(const float4*)&xrow[g + 4];
        float4 x2 = *(const float4*)&xrow[g + 8];
        float4 x3 = *(const float4*)&xrow[g + 12];
        float xr[16] = {x0.x,x0.y,x0.z,x0.w, x1.x,x1.y,x1.z,x1.w,
                        x2.x,x2.y,x2.z,x2.w, x3.x,x3.y,x3.z,x3.w};
        #pragma unroll
        for (int j = 0; j < 16; j++) {
            const int l = g + j;
            float v = fmaf(wdt, sdtr[l], bdtv);
            float dt = fmaxf(v, 0.f) + __logf(1.f + __expf(-fabsf(v)));
            cum += dt;
            float u = dt * xr[j];
            float4 b0 = *(const float4*)&Bt[l][0];
            float4 b1 = *(const float4*)&Bt[l][4];
            float4 b2 = *(const float4*)&Bt[l][8];
            float4 b3 = *(const float4*)&Bt[l][12];
            float bv[16] = {b0.x,b0.y,b0.z,b0.w, b1.x,b1.y,b1.z,b1.w,
                            b2.x,b2.y,b2.z,b2.w, b3.x,b3.y,b3.z,b3.w};
            #pragma unroll
            for (int n = 0; n < 16; n++)
                h[n] = fmaf(exp2f(a2[n] * dt), h[n], u * bv[n]);
        }
    }
    float* hp = &hloc[(((size_t)c * BB + b) * DI + d) * DS];
    *(float4*)&hp[0]  = make_float4(h[0],  h[1],  h[2],  h[3]);
    *(float4*)&hp[4]  = make_float4(h[4],  h[5],  h[6],  h[7]);
    *(float4*)&hp[8]  = make_float4(h[8],  h[9],  h[10], h[11]);
    *(float4*)&hp[12] = make_float4(h[12], h[13], h[14], h[15]);
    sumc[((size_t)c * BB + b) * DI + d] = cum;
}

// ---------------------------------------------------------------------------
// Combine: serial over 64 chunk boundaries, IN-PLACE (hloc becomes hin).
// ---------------------------------------------------------------------------
__global__ __launch_bounds__(256) void combine2_k(float* __restrict__ hloc,
                                                  const float* __restrict__ sumc,
                                                  const float* __restrict__ Alog) {
    const int i = blockIdx.x * 256 + threadIdx.x;   // (b*DI+d)*16+n
    const int n = i & 15;
    const int bd = i >> 4;
    const int d = bd & (DI - 1);
    const float a2 = -expf(Alog[(size_t)d * DS + n]) * 1.44269504f;
    float h = 0.f;
    for (int c = 0; c < NC; c++) {
        size_t idx = ((size_t)c * BB * DI + bd) * DS + n;
        float t = hloc[idx];
        hloc[idx] = h;                              // h entering chunk c
        float P = exp2f(a2 * sumc[(size_t)c * BB * DI + bd]);
        h = fmaf(P, h, t);
    }
}

// ---------------------------------------------------------------------------
// scanB: re-scan chunk with h = hin, emit FINAL y = (yscan + x*Dsk)*silu(z)
// as transposed bf16 ybf[(b*L+l)][d] via LDS 16x256 transpose tiles.
// ---------------------------------------------------------------------------
__global__ __launch_bounds__(256) void scanB_k(const ushort* __restrict__ xzb,  // z half bf16
                                               const float* __restrict__ xc,    // x
                                               const float* __restrict__ xdbl,
                                               const float* __restrict__ Alog,
                                               const float* __restrict__ Wdt,
                                               const float* __restrict__ bdt,
                                               const float* __restrict__ Dskip,
                                               const float* __restrict__ hin,
                                               ushort* __restrict__ ybf) {
    const int blk = blockIdx.x;            // c*16 + b*8 + dblk
    const int dblk = blk & 7;
    const int b = (blk >> 3) & 1;
    const int c = blk >> 4;
    const int tid = threadIdx.x;
    const int d0 = dblk * 256;
    const int d = d0 + tid;

    __shared__ float Bt[LC][16], Ct[LC][16], sdtr[LC];
    __shared__ ushort syt[16][272];        // 16 l x 256 d transpose tile

    float a2[16], h[16];
    #pragma unroll
    for (int n = 0; n < 16; n++)
        a2[n] = -expf(Alog[(size_t)d * DS + n]) * 1.44269504f;
    {
        const float* hp = &hin[(((size_t)c * BB + b) * DI + d) * DS];
        float4 h0 = *(const float4*)&hp[0];
        float4 h1 = *(const float4*)&hp[4];
        float4 h2 = *(const float4*)&hp[8];
        float4 h3 = *(const float4*)&hp[12];
        h[0]=h0.x; h[1]=h0.y; h[2]=h0.z; h[3]=h0.w;
        h[4]=h1.x; h[5]=h1.y; h[6]=h1.z; h[7]=h1.w;
        h[8]=h2.x; h[9]=h2.y; h[10]=h2.z; h[11]=h2.w;
        h[12]=h3.x; h[13]=h3.y; h[14]=h3.z; h[15]=h3.w;
    }
    const float wdt = Wdt[d], bdtv = bdt[d], dsk = Dskip[d];

    #pragma unroll
    for (int i = tid; i < LC * 16; i += 256) {
        int n = i >> 5, l = i & 31;
        Bt[l][n] = xdbl[((size_t)b * KX + 1 + n) * LL + c * LC + l];
        Ct[l][n] = xdbl[((size_t)b * KX + 17 + n) * LL + c * LC + l];
    }
    if (tid < LC) sdtr[tid] = xdbl[(size_t)b * KX * LL + c * LC + tid];
    __syncthreads();

    const float* xrow  = xc + ((size_t)b * DI + d) * LL + c * LC;
    const ushort* zrow = xzb + ((size_t)b * D2 + DI + d) * LL + c * LC;

    for (int g = 0; g < LC; g += 16) {
        float4 x0 = *(const float4*)&xrow[g];
        float4 x1 = *(const float4*)&xrow[g + 4];
        float4 x2 = *(const float4*)&xrow[g + 8];
        float4 x3 = *(const float4*)&xrow[g + 12];
        float xr[16] = {x0.x,x0.y,x0.z,x0.w, x1.x,x1.y,x1.z,x1.w,
                        x2.x,x2.y,x2.z,x2.w, x3.x,x3.y,x3.z,x3.w};
        ushort4 zu0 = *(const ushort4*)&zrow[g];
        ushort4 zu1 = *(const ushort4*)&zrow[g + 4];
        ushort4 zu2 = *(const ushort4*)&zrow[g + 8];
        ushort4 zu3 = *(const ushort4*)&zrow[g + 12];
        float zf[16] = {bf2f(zu0.x),bf2f(zu0.y),bf2f(zu0.z),bf2f(zu0.w),
                        bf2f(zu1.x),bf2f(zu1.y),bf2f(zu1.z),bf2f(zu1.w),
                        bf2f(zu2.x),bf2f(zu2.y),bf2f(zu2.z),bf2f(zu2.w),
                        bf2f(zu3.x),bf2f(zu3.y),bf2f(zu3.z),bf2f(zu3.w)};
        float yf[16];
        #pragma unroll
        for (int j = 0; j < 16; j++) {
            const int l = g + j;
            float v = fmaf(wdt, sdtr[l], bdtv);
            float dt = fmaxf(v, 0.f) + __logf(1.f + __expf(-fabsf(v)));
            float u = dt * xr[j];
            float4 b0 = *(const float4*)&Bt[l][0];
            float4 b1 = *(const float4*)&Bt[l][4];
            float4 b2 = *(const float4*)&Bt[l][8];
            float4 b3 = *(const float4*)&Bt[l][12];
            float4 q0 = *(const float4*)&Ct[l][0];
            float4 q1 = *(const float4*)&Ct[l][4];
            float4 q2 = *(const float4*)&Ct[l][8];
            float4 q3 = *(const float4*)&Ct[l][12];
            float bv[16] = {b0.x,b0.y,b0.z,b0.w, b1.x,b1.y,b1.z,b1.w,
                            b2.x,b2.y,b2.z,b2.w, b3.x,b3.y,b3.z,b3.w};
            float cv[16] = {q0.x,q0.y,q0.z,q0.w, q1.x,q1.y,q1.z,q1.w,
                            q2.x,q2.y,q2.z,q2.w, q3.x,q3.y,q3.z,q3.w};
            float ya = 0.f, yb = 0.f, yc = 0.f, yd = 0.f;
            #pragma unroll
            for (int n = 0; n < 4; n++) {
                h[n]      = fmaf(exp2f(a2[n]      * dt), h[n],      u * bv[n]);
                h[n + 4]  = fmaf(exp2f(a2[n + 4]  * dt), h[n + 4],  u * bv[n + 4]);
                h[n + 8]  = fmaf(exp2f(a2[n + 8]  * dt), h[n + 8],  u * bv[n + 8]);
                h[n + 12] = fmaf(exp2f(a2[n + 12] * dt), h[n + 12], u * bv[n + 12]);
                ya = fmaf(h[n],      cv[n],      ya);
                yb = fmaf(h[n + 4],  cv[n + 4],  yb);
                yc = fmaf(h[n + 8],  cv[n + 8],  yc);
                yd = fmaf(h[n + 12], cv[n + 12], yd);
            }
            float y = fmaf(xr[j], dsk, (ya + yb) + (yc + yd));
            float z = zf[j];
            yf[j] = y * (z / (1.f + __expf(-z)));
        }
        __syncthreads();                       // prev tile's readers done
        #pragma unroll
        for (int j = 0; j < 16; j++) syt[j][tid] = tobf(yf[j]);
        __syncthreads();
        {   // write out 16 l-rows of 256 d, coalesced
            int lrow = tid >> 4, seg = tid & 15;
            uint4 v0 = *(const uint4*)&syt[lrow][seg * 16];
            uint4 v1 = *(const uint4*)&syt[lrow][seg * 16 + 8];
            ushort* orow = &ybf[((size_t)b * LL + c * LC + g + lrow) * DI + d0 + seg * 16];
            *(uint4*)&orow[0] = v0;
            *(uint4*)&orow[8] = v1;
        }
    }
}

// ---------------------------------------------------------------------------
extern "C" void kernel_launch(void* const* d_in, const int* in_sizes, int n_in,
                              void* d_out, int out_size, void* d_ws, size_t ws_size,
                              hipStream_t stream) {
    const float* hs   = (const float*)d_in[0];
    const float* Win  = (const float*)d_in[1];
    const float* cw   = (const float*)d_in[2];
    const float* cb   = (const float*)d_in[3];
    const float* Wx   = (const float*)d_in[4];
    const float* Wdt  = (const float*)d_in[5];
    const float* bdt  = (const float*)d_in[6];
    const float* Alog = (const float*)d_in[7];
    const float* Dsk  = (const float*)d_in[8];
    const float* Wout = (const float*)d_in[9];
    float* out = (float*)d_out;

    // layout (float slots): 25,563,136 f = 102.3 MB (< known-good 126.4 MB)
    // R8 bug fixed: xzb holds BB*D2*LL = 16,777,216 bf16 = 8,388,608 f slots
    // (was wrongly 4,194,304); part slot widened to hold hloc+sumc disjointly.
    float* xzbf  = (float*)d_ws;                           //  8,388,608 f (bf16 xz)
    float* xc    = xzbf  + (size_t)8388608;                //  8,388,608 f
    float* xdbl  = xc    + (size_t)BB * DI * LL;           //    135,168 f
    float* part  = xdbl  + (size_t)BB * KX * LL;           //  slot 4,456,448 f
    float* convf = part  + (size_t)4456448;                //  4,194,304 f region

    ushort* xzb   = (ushort*)xzbf;                         // gemm1 out (bf16), conv+scanB in
    float*  hloc  = part;                                  // 4,194,304 f (scanA -> combine -> scanB)
    float*  sumc  = part + (size_t)4194304;                //   262,144 f (fits slot tail)
    ushort* Winb  = (ushort*)convf;                        // dead after gemm1
    ushort* hsb   = Winb + (size_t)D2 * DM;                // dead after gemm1
    ushort* ybf   = (ushort*)convf;                        // scanB -> gemm2 (8,388,608 u16)
    ushort* Woutb = (ushort*)part;                         // written after scanB (hloc dead)

    cvt2_k<<<4096, 256, 0, stream>>>(Win, hs, (D2 * DM) / 8,
                                     (D2 * DM + BB * LL * DM) / 8, Winb);
    mfma_nt_k<DM, 0><<<dim3(32, 32), 256, 0, stream>>>(Winb, hsb, xzb);
    conv_silu_k<<<BB * DI, 256, 0, stream>>>(xzb, cw, cb, xc);
    xproj_partial_k<<<dim3(8, SEGS), 256, 0, stream>>>(xc, Wx, part);
    xproj_reduce_k<<<(BB * KX * LL / 4 + 255) / 256, 256, 0, stream>>>(part, xdbl);
    scanA_k<<<NC * BB * 8, 256, 0, stream>>>(xc, xdbl, Alog, Wdt, bdt, hloc, sumc);
    combine2_k<<<(BB * DI * DS) / 256, 256, 0, stream>>>(hloc, sumc, Alog);
    scanB_k<<<NC * BB * 8, 256, 0, stream>>>(xzb, xc, xdbl, Alog, Wdt, bdt, Dsk, hloc, ybf);
    cvt_bf16_k<<<1024, 256, 0, stream>>>(Wout, Woutb, (DM * DI) / 8);
    mfma_nt_k<DI, 1><<<dim3(8, 32), 256, 0, stream>>>(ybf, Woutb, out);
}

// Round 10
// 251.131 us; speedup vs baseline: 1.0882x; 1.0882x over previous
//
#include <hip/hip_runtime.h>
#include <hip/hip_bf16.h>
#include <hip/hip_fp16.h>
#include <math.h>

#define BB 2
#define LL 2048
#define DM 1024
#define DS 16
#define DI 2048
#define KX 33          // 1 + 2*D_STATE
#define D2 (2*DI)      // 4096
#define NC 64          // scan chunks
#define LC 32          // chunk length (NC*LC == LL)
#define SEGS 32        // xproj d-segments
#define SEGW 64        // d per segment

typedef __attribute__((ext_vector_type(8))) short short8v;   // 8 bf16 (4 VGPRs)
typedef __attribute__((ext_vector_type(4))) float f32x4;

__device__ __forceinline__ void gload16(const void* g, void* l) {
    __builtin_amdgcn_global_load_lds((const __attribute__((address_space(1))) void*)g,
                                     (__attribute__((address_space(3))) void*)l,
                                     16, 0, 0);
}

__device__ __forceinline__ ushort tobf(float v) {
    __hip_bfloat16 h = __float2bfloat16(v);
    return *(ushort*)&h;
}
__device__ __forceinline__ float bf2f(ushort u) {
    return __uint_as_float((unsigned)u << 16);
}
__device__ __forceinline__ ushort tof16(float v) {
    __half h = __float2half(v);
    return *(ushort*)&h;
}
__device__ __forceinline__ float f162f(ushort u) {
    __half h = *(__half*)&u;
    return __half2float(h);
}

// ---------------------------------------------------------------------------
// merged fp32 -> bf16 conversion for Win then hs into one contiguous region
// ---------------------------------------------------------------------------
__global__ __launch_bounds__(256) void cvt2_k(const float* __restrict__ a,
                                              const float* __restrict__ b,
                                              int na8, int ntot8,
                                              ushort* __restrict__ o) {
    int i = blockIdx.x * 256 + threadIdx.x;
    if (i >= ntot8) return;
    const float* src = (i < na8) ? &a[(size_t)i * 8] : &b[(size_t)(i - na8) * 8];
    float4 v0 = *(const float4*)&src[0];
    float4 v1 = *(const float4*)&src[4];
    float v[8] = {v0.x, v0.y, v0.z, v0.w, v1.x, v1.y, v1.z, v1.w};
    ushort u[8];
    #pragma unroll
    for (int j = 0; j < 8; j++) u[j] = tobf(v[j]);
    *(ushort4*)&o[(size_t)i * 8]     = make_ushort4(u[0], u[1], u[2], u[3]);
    *(ushort4*)&o[(size_t)i * 8 + 4] = make_ushort4(u[4], u[5], u[6], u[7]);
}

__global__ __launch_bounds__(256) void cvt_bf16_k(const float* __restrict__ in,
                                                  ushort* __restrict__ o, int n8) {
    int i = blockIdx.x * 256 + threadIdx.x;
    if (i >= n8) return;
    float4 a = *(const float4*)&in[(size_t)i * 8];
    float4 b = *(const float4*)&in[(size_t)i * 8 + 4];
    float v[8] = {a.x, a.y, a.z, a.w, b.x, b.y, b.z, b.w};
    ushort u[8];
    #pragma unroll
    for (int j = 0; j < 8; j++) u[j] = tobf(v[j]);
    *(ushort4*)&o[(size_t)i * 8]     = make_ushort4(u[0], u[1], u[2], u[3]);
    *(ushort4*)&o[(size_t)i * 8 + 4] = make_ushort4(u[4], u[5], u[6], u[7]);
}

// ---------------------------------------------------------------------------
// NT bf16 MFMA GEMM (m97 structure), 128x128 tile, 4 waves, 4x4 fragments.
// MODE 0: C bf16, row=d, col=bl -> xzb[((col>>11)*D2 + row)*LL + (col&2047)]
// MODE 1: C fp32, row=bl, col=m -> out[row*DM + col]
// ---------------------------------------------------------------------------
template<int K, int MODE>
__global__ __launch_bounds__(256) void mfma_nt_k(const ushort* __restrict__ A,
                                                 const ushort* __restrict__ Bm,
                                                 void* __restrict__ Cout) {
    __shared__ ushort Als[128][32];
    __shared__ ushort Bls[128][32];
    const int n0 = blockIdx.x * 128;
    const int m0 = blockIdx.y * 128;
    const int tid = threadIdx.x;
    const int w = tid >> 6, lane = tid & 63;
    const int wr = (w >> 1) * 64, wc = (w & 1) * 64;
    const int lrow = lane & 15;
    const int kq = lane >> 4;

    const int srow = (lane >> 2);
    const int skof = (lane & 3) * 8;

    f32x4 acc[4][4] = {};
    for (int k0 = 0; k0 < K; k0 += 32) {
        #pragma unroll
        for (int j = 0; j < 2; j++) {
            const int rbase = w * 32 + j * 16;
            gload16(&A [(size_t)(m0 + rbase + srow) * K + k0 + skof], &Als[rbase][0]);
            gload16(&Bm[(size_t)(n0 + rbase + srow) * K + k0 + skof], &Bls[rbase][0]);
        }
        __syncthreads();
        short8v af[4], bf[4];
        #pragma unroll
        for (int i = 0; i < 4; i++) {
            af[i] = *(const short8v*)&Als[wr + i * 16 + lrow][kq * 8];
            bf[i] = *(const short8v*)&Bls[wc + i * 16 + lrow][kq * 8];
        }
        #pragma unroll
        for (int i = 0; i < 4; i++)
            #pragma unroll
            for (int jn = 0; jn < 4; jn++)
                acc[i][jn] = __builtin_amdgcn_mfma_f32_16x16x32_bf16(af[i], bf[jn], acc[i][jn], 0, 0, 0);
        __syncthreads();
    }
    #pragma unroll
    for (int i = 0; i < 4; i++) {
        #pragma unroll
        for (int jn = 0; jn < 4; jn++) {
            #pragma unroll
            for (int r = 0; r < 4; r++) {
                int row = m0 + wr + i * 16 + (lane >> 4) * 4 + r;
                int col = n0 + wc + jn * 16 + (lane & 15);
                if constexpr (MODE == 0) {
                    size_t off = ((size_t)(col >> 11) * D2 + row) * LL + (col & (LL - 1));
                    ((ushort*)Cout)[off] = tobf(acc[i][jn][r]);
                } else {
                    ((float*)Cout)[(size_t)row * DM + col] = acc[i][jn][r];
                }
            }
        }
    }
}

// ---------------------------------------------------------------------------
// Depthwise causal conv(4) + bias + SiLU on bf16 x-half of xzb -> xc (fp32)
// ---------------------------------------------------------------------------
__global__ __launch_bounds__(256) void conv_silu_k(const ushort* __restrict__ xzb,
                                                   const float* __restrict__ cw,
                                                   const float* __restrict__ cb,
                                                   float* __restrict__ xc) {
    const int row = blockIdx.x;             // 0..B*DI-1
    const int b = row >> 11, d = row & (DI - 1);
    const ushort* xr = xzb + ((size_t)b * D2 + d) * LL;
    float4 wv = *(const float4*)&cw[d * 4];
    const float w0 = wv.x, w1 = wv.y, w2 = wv.z, w3 = wv.w;
    const float bias = cb[d];
    const int l0 = threadIdx.x * 8;
    ushort4 pv = (l0 >= 4) ? *(const ushort4*)&xr[l0 - 4]
                           : make_ushort4(0, 0, 0, 0);
    ushort4 c0 = *(const ushort4*)&xr[l0];
    ushort4 c1 = *(const ushort4*)&xr[l0 + 4];
    float buf[11] = {bf2f(pv.y), bf2f(pv.z), bf2f(pv.w),
                     bf2f(c0.x), bf2f(c0.y), bf2f(c0.z), bf2f(c0.w),
                     bf2f(c1.x), bf2f(c1.y), bf2f(c1.z), bf2f(c1.w)};
    float o[8];
    #pragma unroll
    for (int j = 0; j < 8; j++) {
        float s = fmaf(buf[j], w0, fmaf(buf[j + 1], w1,
                  fmaf(buf[j + 2], w2, fmaf(buf[j + 3], w3, bias))));
        o[j] = s / (1.f + __expf(-s));
    }
    float* out = xc + ((size_t)b * DI + d) * LL + l0;
    *(float4*)&out[0] = make_float4(o[0], o[1], o[2], o[3]);
    *(float4*)&out[4] = make_float4(o[4], o[5], o[6], o[7]);
}

// ---------------------------------------------------------------------------
// x_dbl partials: part[seg][b][k][l] = sum_{d in seg(64)} xc[b][d][l]*Wx[k][d]
// ---------------------------------------------------------------------------
__global__ __launch_bounds__(256) void xproj_partial_k(const float* __restrict__ xc,
                                                       const float* __restrict__ Wx,
                                                       float* __restrict__ part) {
    const int lt = blockIdx.x;             // 0..7  (512 l each)
    const int seg = blockIdx.y;            // 0..31 (64 d each)
    const int tid = threadIdx.x;
    const int bl0 = lt * 512;
    const int b = bl0 >> 11;
    const int l = (bl0 & (LL - 1)) + tid * 2;
    const int dbase = seg * SEGW;

    __shared__ float w[SEGW][36];          // [dd][kk], row padded to 36
    for (int kk = tid >> 6; kk < KX; kk += 4)
        w[tid & 63][kk] = Wx[(size_t)kk * DI + dbase + (tid & 63)];
    __syncthreads();

    float2 acc[KX];
    #pragma unroll
    for (int kk = 0; kk < KX; kk++) acc[kk] = make_float2(0.f, 0.f);

    const float* xb = xc + ((size_t)b * DI + dbase) * LL + l;
    #pragma unroll 4
    for (int dd = 0; dd < SEGW; dd++) {
        float2 xv = *(const float2*)&xb[(size_t)dd * LL];
        #pragma unroll
        for (int q = 0; q < 8; q++) {
            float4 wv = *(const float4*)&w[dd][q * 4];
            float wa[4] = {wv.x, wv.y, wv.z, wv.w};
            #pragma unroll
            for (int t = 0; t < 4; t++) {
                acc[q * 4 + t].x = fmaf(xv.x, wa[t], acc[q * 4 + t].x);
                acc[q * 4 + t].y = fmaf(xv.y, wa[t], acc[q * 4 + t].y);
            }
        }
        float wl = w[dd][32];
        acc[32].x = fmaf(xv.x, wl, acc[32].x);
        acc[32].y = fmaf(xv.y, wl, acc[32].y);
    }
    #pragma unroll
    for (int kk = 0; kk < KX; kk++)
        *(float2*)&part[(((size_t)seg * BB + b) * KX + kk) * LL + l] = acc[kk];
}

__global__ __launch_bounds__(256) void xproj_reduce_k(const float* __restrict__ part,
                                                      float* __restrict__ xdbl) {
    const int i = blockIdx.x * 256 + threadIdx.x;    // float4 index
    if (i >= (BB * KX * LL) / 4) return;
    float4 s = make_float4(0.f, 0.f, 0.f, 0.f);
    #pragma unroll
    for (int seg = 0; seg < SEGS; seg++) {
        float4 v = *(const float4*)&part[(size_t)seg * BB * KX * LL + (size_t)i * 4];
        s.x += v.x; s.y += v.y; s.z += v.z; s.w += v.w;
    }
    *(float4*)&xdbl[(size_t)i * 4] = s;
}

// ---------------------------------------------------------------------------
// Merged local scan (R7-proven structure): thread-per-d, 16 states in regs.
// dt inline; writes y0 (+x*Dskip) fp32 in-place over xc, cum as fp16 -> cumh,
// terminal h -> hloc, chunk dt-sum -> sumc. No cross-lane ops.
// ---------------------------------------------------------------------------
__global__ __launch_bounds__(256) void scan_local_k(float* xc,     // x in / y0 out
                                                    const float* __restrict__ xdbl,
                                                    const float* __restrict__ Alog,
                                                    const float* __restrict__ Wdt,
                                                    const float* __restrict__ bdt,
                                                    const float* __restrict__ Dskip,
                                                    float* __restrict__ hloc,
                                                    float* __restrict__ sumc,
                                                    ushort* __restrict__ cumh) {
    const int blk = blockIdx.x;            // c*16 + b*8 + dblk
    const int dblk = blk & 7;
    const int b = (blk >> 3) & 1;
    const int c = blk >> 4;
    const int tid = threadIdx.x;
    const int d = dblk * 256 + tid;

    __shared__ float Bt[LC][16], Ct[LC][16], sdtr[LC];

    float a2[16], h[16];
    #pragma unroll
    for (int n = 0; n < 16; n++) {
        a2[n] = -expf(Alog[(size_t)d * DS + n]) * 1.44269504f;
        h[n] = 0.f;
    }
    const float wdt = Wdt[d], bdtv = bdt[d], dsk = Dskip[d];

    #pragma unroll
    for (int i = tid; i < LC * 16; i += 256) {           // 2 iters
        int n = i >> 5, l = i & 31;
        Bt[l][n] = xdbl[((size_t)b * KX + 1 + n) * LL + c * LC + l];
        Ct[l][n] = xdbl[((size_t)b * KX + 17 + n) * LL + c * LC + l];
    }
    if (tid < LC) sdtr[tid] = xdbl[(size_t)b * KX * LL + c * LC + tid];
    __syncthreads();

    float cum = 0.f;
    float* xrow = xc + ((size_t)b * DI + d) * LL + c * LC;
    ushort* cumrow = cumh + ((size_t)b * DI + d) * LL + c * LC;

    for (int g = 0; g < LC; g += 16) {
        float4 x0 = *(const float4*)&xrow[g];
        float4 x1 = *(const float4*)&xrow[g + 4];
        float4 x2 = *(const float4*)&xrow[g + 8];
        float4 x3 = *(const float4*)&xrow[g + 12];
        float xr[16] = {x0.x,x0.y,x0.z,x0.w, x1.x,x1.y,x1.z,x1.w,
                        x2.x,x2.y,x2.z,x2.w, x3.x,x3.y,x3.z,x3.w};
        float cwv[16];
        #pragma unroll
        for (int j = 0; j < 16; j++) {
            const int l = g + j;
            float v = fmaf(wdt, sdtr[l], bdtv);
            float dt = fmaxf(v, 0.f) + __logf(1.f + __expf(-fabsf(v)));  // fast softplus
            cum += dt; cwv[j] = cum;
            float u = dt * xr[j];
            float4 b0 = *(const float4*)&Bt[l][0];
            float4 b1 = *(const float4*)&Bt[l][4];
            float4 b2 = *(const float4*)&Bt[l][8];
            float4 b3 = *(const float4*)&Bt[l][12];
            float4 q0 = *(const float4*)&Ct[l][0];
            float4 q1 = *(const float4*)&Ct[l][4];
            float4 q2 = *(const float4*)&Ct[l][8];
            float4 q3 = *(const float4*)&Ct[l][12];
            float bv[16] = {b0.x,b0.y,b0.z,b0.w, b1.x,b1.y,b1.z,b1.w,
                            b2.x,b2.y,b2.z,b2.w, b3.x,b3.y,b3.z,b3.w};
            float cv[16] = {q0.x,q0.y,q0.z,q0.w, q1.x,q1.y,q1.z,q1.w,
                            q2.x,q2.y,q2.z,q2.w, q3.x,q3.y,q3.z,q3.w};
            float ya = 0.f, yb = 0.f, yc = 0.f, yd = 0.f;
            #pragma unroll
            for (int n = 0; n < 4; n++) {
                h[n]      = fmaf(exp2f(a2[n]      * dt), h[n],      u * bv[n]);
                h[n + 4]  = fmaf(exp2f(a2[n + 4]  * dt), h[n + 4],  u * bv[n + 4]);
                h[n + 8]  = fmaf(exp2f(a2[n + 8]  * dt), h[n + 8],  u * bv[n + 8]);
                h[n + 12] = fmaf(exp2f(a2[n + 12] * dt), h[n + 12], u * bv[n + 12]);
                ya = fmaf(h[n],      cv[n],      ya);
                yb = fmaf(h[n + 4],  cv[n + 4],  yb);
                yc = fmaf(h[n + 8],  cv[n + 8],  yc);
                yd = fmaf(h[n + 12], cv[n + 12], yd);
            }
            xr[j] = fmaf(xr[j], dsk, (ya + yb) + (yc + yd));   // y0
        }
        *(float4*)&xrow[g]      = make_float4(xr[0],  xr[1],  xr[2],  xr[3]);
        *(float4*)&xrow[g + 4]  = make_float4(xr[4],  xr[5],  xr[6],  xr[7]);
        *(float4*)&xrow[g + 8]  = make_float4(xr[8],  xr[9],  xr[10], xr[11]);
        *(float4*)&xrow[g + 12] = make_float4(xr[12], xr[13], xr[14], xr[15]);
        *(ushort4*)&cumrow[g]      = make_ushort4(tof16(cwv[0]),  tof16(cwv[1]),  tof16(cwv[2]),  tof16(cwv[3]));
        *(ushort4*)&cumrow[g + 4]  = make_ushort4(tof16(cwv[4]),  tof16(cwv[5]),  tof16(cwv[6]),  tof16(cwv[7]));
        *(ushort4*)&cumrow[g + 8]  = make_ushort4(tof16(cwv[8]),  tof16(cwv[9]),  tof16(cwv[10]), tof16(cwv[11]));
        *(ushort4*)&cumrow[g + 12] = make_ushort4(tof16(cwv[12]), tof16(cwv[13]), tof16(cwv[14]), tof16(cwv[15]));
    }
    float* hp = &hloc[(((size_t)c * BB + b) * DI + d) * DS];
    *(float4*)&hp[0]  = make_float4(h[0],  h[1],  h[2],  h[3]);
    *(float4*)&hp[4]  = make_float4(h[4],  h[5],  h[6],  h[7]);
    *(float4*)&hp[8]  = make_float4(h[8],  h[9],  h[10], h[11]);
    *(float4*)&hp[12] = make_float4(h[12], h[13], h[14], h[15]);
    sumc[((size_t)c * BB + b) * DI + d] = cum;
}

// ---------------------------------------------------------------------------
// Combine: serial over 64 chunk boundaries, IN-PLACE (hloc becomes hin).
// ---------------------------------------------------------------------------
__global__ __launch_bounds__(256) void combine2_k(float* __restrict__ hloc,
                                                  const float* __restrict__ sumc,
                                                  const float* __restrict__ Alog) {
    const int i = blockIdx.x * 256 + threadIdx.x;   // (b*DI+d)*16+n
    const int n = i & 15;
    const int bd = i >> 4;
    const int d = bd & (DI - 1);
    const float a2 = -expf(Alog[(size_t)d * DS + n]) * 1.44269504f;
    float h = 0.f;
    for (int c = 0; c < NC; c++) {
        size_t idx = ((size_t)c * BB * DI + bd) * DS + n;
        float t = hloc[idx];
        hloc[idx] = h;                              // h entering chunk c
        float P = exp2f(a2 * sumc[(size_t)c * BB * DI + bd]);
        h = fmaf(P, h, t);
    }
}

// ---------------------------------------------------------------------------
// y fixup (fully parallel): y = (y0 + sum_n C[n,l]*exp2(a2*cum[l])*hin[n])
//                               * silu(z),  z from bf16 xzb, cum from fp16.
// Emitted transposed bf16 ybf[(b*L+l)][d].
// ---------------------------------------------------------------------------
__global__ __launch_bounds__(256) void yfix_k(const ushort* __restrict__ xzb,  // z half bf16
                                              const ushort* __restrict__ cumh, // fp16 cum
                                              const float* __restrict__ xc,    // y0
                                              const float* __restrict__ xdbl,
                                              const float* __restrict__ Alog,
                                              const float* __restrict__ hin,
                                              ushort* __restrict__ ybf) {
    const int bl0 = blockIdx.x * 64;
    const int b = bl0 >> 11, l0 = bl0 & (LL - 1);
    const int d0 = blockIdx.y * 64;
    const int tid = threadIdx.x;
    const int dl = tid & 63;
    const int lq = tid >> 6;                  // 0..3 -> 16 l's each
    const int d = d0 + dl;
    const int lbase = l0 + lq * 16;
    const int c = lbase / LC;                 // chunk of this 16-l subgroup

    __shared__ float Ctile[64][16];           // [l][n]
    __shared__ ushort sy[64][72];             // bf16 transpose tile (padded)

    {   // stage C
        int li = tid & 63, n4 = (tid >> 6) * 4;
        #pragma unroll
        for (int k = 0; k < 4; k++)
            Ctile[li][n4 + k] = xdbl[((size_t)b * KX + 17 + n4 + k) * LL + l0 + li];
    }
    float a2[16], hi[16];
    #pragma unroll
    for (int n = 0; n < 16; n++)
        a2[n] = -expf(Alog[(size_t)d * DS + n]) * 1.44269504f;
    {
        const float* hp = &hin[(((size_t)c * BB + b) * DI + d) * DS];
        float4 h0 = *(const float4*)&hp[0];
        float4 h1 = *(const float4*)&hp[4];
        float4 h2 = *(const float4*)&hp[8];
        float4 h3 = *(const float4*)&hp[12];
        hi[0]=h0.x; hi[1]=h0.y; hi[2]=h0.z; hi[3]=h0.w;
        hi[4]=h1.x; hi[5]=h1.y; hi[6]=h1.z; hi[7]=h1.w;
        hi[8]=h2.x; hi[9]=h2.y; hi[10]=h2.z; hi[11]=h2.w;
        hi[12]=h3.x; hi[13]=h3.y; hi[14]=h3.z; hi[15]=h3.w;
    }
    const ushort* cumr = cumh + ((size_t)b * DI + d) * LL + lbase;
    const float*  y0r  = xc   + ((size_t)b * DI + d) * LL + lbase;
    const ushort* zr   = xzb  + ((size_t)b * D2 + DI + d) * LL + lbase;
    ushort4 cu0 = *(const ushort4*)&cumr[0],  cu1 = *(const ushort4*)&cumr[4];
    ushort4 cu2 = *(const ushort4*)&cumr[8],  cu3 = *(const ushort4*)&cumr[12];
    float4 y0v = *(const float4*)&y0r[0],  y1v = *(const float4*)&y0r[4];
    float4 y2v = *(const float4*)&y0r[8],  y3v = *(const float4*)&y0r[12];
    ushort4 zu0 = *(const ushort4*)&zr[0], zu1 = *(const ushort4*)&zr[4];
    ushort4 zu2 = *(const ushort4*)&zr[8], zu3 = *(const ushort4*)&zr[12];
    float cm[16] = {f162f(cu0.x),f162f(cu0.y),f162f(cu0.z),f162f(cu0.w),
                    f162f(cu1.x),f162f(cu1.y),f162f(cu1.z),f162f(cu1.w),
                    f162f(cu2.x),f162f(cu2.y),f162f(cu2.z),f162f(cu2.w),
                    f162f(cu3.x),f162f(cu3.y),f162f(cu3.z),f162f(cu3.w)};
    float yv[16] = {y0v.x,y0v.y,y0v.z,y0v.w, y1v.x,y1v.y,y1v.z,y1v.w,
                    y2v.x,y2v.y,y2v.z,y2v.w, y3v.x,y3v.y,y3v.z,y3v.w};
    float zv[16] = {bf2f(zu0.x),bf2f(zu0.y),bf2f(zu0.z),bf2f(zu0.w),
                    bf2f(zu1.x),bf2f(zu1.y),bf2f(zu1.z),bf2f(zu1.w),
                    bf2f(zu2.x),bf2f(zu2.y),bf2f(zu2.z),bf2f(zu2.w),
                    bf2f(zu3.x),bf2f(zu3.y),bf2f(zu3.z),bf2f(zu3.w)};
    __syncthreads();
    #pragma unroll
    for (int j = 0; j < 16; j++) {
        int lidx = lq * 16 + j;
        float4 a0 = *(const float4*)&Ctile[lidx][0];
        float4 a1 = *(const float4*)&Ctile[lidx][4];
        float4 a2v = *(const float4*)&Ctile[lidx][8];
        float4 a3 = *(const float4*)&Ctile[lidx][12];
        float cv[16] = {a0.x,a0.y,a0.z,a0.w, a1.x,a1.y,a1.z,a1.w,
                        a2v.x,a2v.y,a2v.z,a2v.w, a3.x,a3.y,a3.z,a3.w};
        float corr = 0.f;
        #pragma unroll
        for (int n = 0; n < 16; n++)
            corr = fmaf(cv[n] * hi[n], exp2f(a2[n] * cm[j]), corr);
        float z = zv[j];
        float zs = z / (1.f + __expf(-z));
        float y = (yv[j] + corr) * zs;
        sy[lidx][dl] = tobf(y);
    }
    __syncthreads();
    {
        int lw = tid >> 2, p = tid & 3;
        uint4 v0 = *(const uint4*)&sy[lw][p * 16];
        uint4 v1 = *(const uint4*)&sy[lw][p * 16 + 8];
        ushort* orow = &ybf[((size_t)b * LL + l0 + lw) * DI + d0 + p * 16];
        *(uint4*)&orow[0] = v0;
        *(uint4*)&orow[8] = v1;
    }
}

// ---------------------------------------------------------------------------
extern "C" void kernel_launch(void* const* d_in, const int* in_sizes, int n_in,
                              void* d_out, int out_size, void* d_ws, size_t ws_size,
                              hipStream_t stream) {
    const float* hs   = (const float*)d_in[0];
    const float* Win  = (const float*)d_in[1];
    const float* cw   = (const float*)d_in[2];
    const float* cb   = (const float*)d_in[3];
    const float* Wx   = (const float*)d_in[4];
    const float* Wdt  = (const float*)d_in[5];
    const float* bdt  = (const float*)d_in[6];
    const float* Alog = (const float*)d_in[7];
    const float* Dsk  = (const float*)d_in[8];
    const float* Wout = (const float*)d_in[9];
    float* out = (float*)d_out;

    // ---- layout (float slots), total 29,757,440 f = 119.0 MB (< 126.8 proven)
    // slot map / liveness:
    //  xzbf  [8,388,608] : bf16 xz     (gemm1 -> conv(x), yfix(z))
    //  xc    [8,388,608] : x fp32      (conv -> xproj, scan: y0 in-place -> yfix)
    //  xdbl  [  135,168] : x_dbl       (reduce -> scan/yfix)
    //  slot1 [8,650,752] : part(4,325,376; dead after reduce)
    //                      -> hloc(4,194,304)+sumc(262,144) @ [0..4,456,448)
    //                      ybf(4,194,304 f = 8.4M u16)      @ [4,456,448..)
    //                      Woutb(1,048,576 f) @ [0..) after yfix (hin dead)
    //  slot2 [4,194,304] : Winb+hsb (8.4M u16; dead after gemm1)
    //                      -> cumh (8.4M u16 fp16, scan -> yfix)
    float* xzbf  = (float*)d_ws;
    float* xc    = xzbf  + (size_t)8388608;
    float* xdbl  = xc    + (size_t)8388608;
    float* slot1 = xdbl  + (size_t)135168;
    float* slot2 = slot1 + (size_t)8650752;

    ushort* xzb   = (ushort*)xzbf;
    float*  part  = slot1;
    float*  hloc  = slot1;
    float*  sumc  = slot1 + (size_t)4194304;
    ushort* ybf   = (ushort*)(slot1 + (size_t)4456448);
    ushort* Woutb = (ushort*)slot1;
    ushort* Winb  = (ushort*)slot2;
    ushort* hsb   = Winb + (size_t)D2 * DM;
    ushort* cumh  = (ushort*)slot2;

    cvt2_k<<<4096, 256, 0, stream>>>(Win, hs, (D2 * DM) / 8,
                                     (D2 * DM + BB * LL * DM) / 8, Winb);
    mfma_nt_k<DM, 0><<<dim3(32, 32), 256, 0, stream>>>(Winb, hsb, xzb);
    conv_silu_k<<<BB * DI, 256, 0, stream>>>(xzb, cw, cb, xc);
    xproj_partial_k<<<dim3(8, SEGS), 256, 0, stream>>>(xc, Wx, part);
    xproj_reduce_k<<<(BB * KX * LL / 4 + 255) / 256, 256, 0, stream>>>(part, xdbl);
    scan_local_k<<<NC * BB * 8, 256, 0, stream>>>(xc, xdbl, Alog, Wdt, bdt, Dsk,
                                                  hloc, sumc, cumh);
    combine2_k<<<(BB * DI * DS) / 256, 256, 0, stream>>>(hloc, sumc, Alog);
    yfix_k<<<dim3((BB * LL) / 64, DI / 64), 256, 0, stream>>>(xzb, cumh, xc, xdbl,
                                                              Alog, hloc, ybf);
    cvt_bf16_k<<<1024, 256, 0, stream>>>(Wout, Woutb, (DM * DI) / 8);
    mfma_nt_k<DI, 1><<<dim3(8, 32), 256, 0, stream>>>(ybf, Woutb, out);
}

// Round 11
// 228.660 us; speedup vs baseline: 1.1952x; 1.0983x over previous
//
#include <hip/hip_runtime.h>
#include <hip/hip_bf16.h>
#include <hip/hip_fp16.h>
#include <math.h>

#define BB 2
#define LL 2048
#define DM 1024
#define DS 16
#define DI 2048
#define KX 33          // 1 + 2*D_STATE
#define D2 (2*DI)      // 4096
#define NC 64          // scan chunks
#define LC 32          // chunk length (NC*LC == LL)
#define SEGS 32        // xproj d-segments
#define SEGW 64        // d per segment

typedef __attribute__((ext_vector_type(8))) short short8v;   // 8 bf16 (4 VGPRs)
typedef __attribute__((ext_vector_type(4))) float f32x4;

__device__ __forceinline__ void gload16(const void* g, void* l) {
    __builtin_amdgcn_global_load_lds((const __attribute__((address_space(1))) void*)g,
                                     (__attribute__((address_space(3))) void*)l,
                                     16, 0, 0);
}

__device__ __forceinline__ ushort tobf(float v) {
    __hip_bfloat16 h = __float2bfloat16(v);
    return *(ushort*)&h;
}
__device__ __forceinline__ float bf2f(ushort u) {
    return __uint_as_float((unsigned)u << 16);
}
__device__ __forceinline__ ushort tof16(float v) {
    __half h = __float2half(v);
    return *(ushort*)&h;
}
__device__ __forceinline__ float f162f(ushort u) {
    __half h = *(__half*)&u;
    return __half2float(h);
}
// raw v_exp_f32 — single instruction; inputs here are always <= 0 (safe range)
__device__ __forceinline__ float fexp2(float x) {
    return __builtin_amdgcn_exp2f(x);
}

// ---------------------------------------------------------------------------
// merged fp32 -> bf16 conversion for Win then hs into one contiguous region
// ---------------------------------------------------------------------------
__global__ __launch_bounds__(256) void cvt2_k(const float* __restrict__ a,
                                              const float* __restrict__ b,
                                              int na8, int ntot8,
                                              ushort* __restrict__ o) {
    int i = blockIdx.x * 256 + threadIdx.x;
    if (i >= ntot8) return;
    const float* src = (i < na8) ? &a[(size_t)i * 8] : &b[(size_t)(i - na8) * 8];
    float4 v0 = *(const float4*)&src[0];
    float4 v1 = *(const float4*)&src[4];
    float v[8] = {v0.x, v0.y, v0.z, v0.w, v1.x, v1.y, v1.z, v1.w};
    ushort u[8];
    #pragma unroll
    for (int j = 0; j < 8; j++) u[j] = tobf(v[j]);
    *(ushort4*)&o[(size_t)i * 8]     = make_ushort4(u[0], u[1], u[2], u[3]);
    *(ushort4*)&o[(size_t)i * 8 + 4] = make_ushort4(u[4], u[5], u[6], u[7]);
}

__global__ __launch_bounds__(256) void cvt_bf16_k(const float* __restrict__ in,
                                                  ushort* __restrict__ o, int n8) {
    int i = blockIdx.x * 256 + threadIdx.x;
    if (i >= n8) return;
    float4 a = *(const float4*)&in[(size_t)i * 8];
    float4 b = *(const float4*)&in[(size_t)i * 8 + 4];
    float v[8] = {a.x, a.y, a.z, a.w, b.x, b.y, b.z, b.w};
    ushort u[8];
    #pragma unroll
    for (int j = 0; j < 8; j++) u[j] = tobf(v[j]);
    *(ushort4*)&o[(size_t)i * 8]     = make_ushort4(u[0], u[1], u[2], u[3]);
    *(ushort4*)&o[(size_t)i * 8 + 4] = make_ushort4(u[4], u[5], u[6], u[7]);
}

// ---------------------------------------------------------------------------
// NT bf16 MFMA GEMM (m97 structure), 128x128 tile, 4 waves, 4x4 fragments.
// MODE 0: C bf16, row=d, col=bl -> xzb[((col>>11)*D2 + row)*LL + (col&2047)]
// MODE 1: C fp32, row=bl, col=m -> out[row*DM + col]
// ---------------------------------------------------------------------------
template<int K, int MODE>
__global__ __launch_bounds__(256) void mfma_nt_k(const ushort* __restrict__ A,
                                                 const ushort* __restrict__ Bm,
                                                 void* __restrict__ Cout) {
    __shared__ ushort Als[128][32];
    __shared__ ushort Bls[128][32];
    const int n0 = blockIdx.x * 128;
    const int m0 = blockIdx.y * 128;
    const int tid = threadIdx.x;
    const int w = tid >> 6, lane = tid & 63;
    const int wr = (w >> 1) * 64, wc = (w & 1) * 64;
    const int lrow = lane & 15;
    const int kq = lane >> 4;

    const int srow = (lane >> 2);
    const int skof = (lane & 3) * 8;

    f32x4 acc[4][4] = {};
    for (int k0 = 0; k0 < K; k0 += 32) {
        #pragma unroll
        for (int j = 0; j < 2; j++) {
            const int rbase = w * 32 + j * 16;
            gload16(&A [(size_t)(m0 + rbase + srow) * K + k0 + skof], &Als[rbase][0]);
            gload16(&Bm[(size_t)(n0 + rbase + srow) * K + k0 + skof], &Bls[rbase][0]);
        }
        __syncthreads();
        short8v af[4], bf[4];
        #pragma unroll
        for (int i = 0; i < 4; i++) {
            af[i] = *(const short8v*)&Als[wr + i * 16 + lrow][kq * 8];
            bf[i] = *(const short8v*)&Bls[wc + i * 16 + lrow][kq * 8];
        }
        #pragma unroll
        for (int i = 0; i < 4; i++)
            #pragma unroll
            for (int jn = 0; jn < 4; jn++)
                acc[i][jn] = __builtin_amdgcn_mfma_f32_16x16x32_bf16(af[i], bf[jn], acc[i][jn], 0, 0, 0);
        __syncthreads();
    }
    #pragma unroll
    for (int i = 0; i < 4; i++) {
        #pragma unroll
        for (int jn = 0; jn < 4; jn++) {
            #pragma unroll
            for (int r = 0; r < 4; r++) {
                int row = m0 + wr + i * 16 + (lane >> 4) * 4 + r;
                int col = n0 + wc + jn * 16 + (lane & 15);
                if constexpr (MODE == 0) {
                    size_t off = ((size_t)(col >> 11) * D2 + row) * LL + (col & (LL - 1));
                    ((ushort*)Cout)[off] = tobf(acc[i][jn][r]);
                } else {
                    ((float*)Cout)[(size_t)row * DM + col] = acc[i][jn][r];
                }
            }
        }
    }
}

// ---------------------------------------------------------------------------
// Depthwise causal conv(4) + bias + SiLU on bf16 x-half of xzb -> xc (fp32)
// ---------------------------------------------------------------------------
__global__ __launch_bounds__(256) void conv_silu_k(const ushort* __restrict__ xzb,
                                                   const float* __restrict__ cw,
                                                   const float* __restrict__ cb,
                                                   float* __restrict__ xc) {
    const int row = blockIdx.x;             // 0..B*DI-1
    const int b = row >> 11, d = row & (DI - 1);
    const ushort* xr = xzb + ((size_t)b * D2 + d) * LL;
    float4 wv = *(const float4*)&cw[d * 4];
    const float w0 = wv.x, w1 = wv.y, w2 = wv.z, w3 = wv.w;
    const float bias = cb[d];
    const int l0 = threadIdx.x * 8;
    ushort4 pv = (l0 >= 4) ? *(const ushort4*)&xr[l0 - 4]
                           : make_ushort4(0, 0, 0, 0);
    ushort4 c0 = *(const ushort4*)&xr[l0];
    ushort4 c1 = *(const ushort4*)&xr[l0 + 4];
    float buf[11] = {bf2f(pv.y), bf2f(pv.z), bf2f(pv.w),
                     bf2f(c0.x), bf2f(c0.y), bf2f(c0.z), bf2f(c0.w),
                     bf2f(c1.x), bf2f(c1.y), bf2f(c1.z), bf2f(c1.w)};
    float o[8];
    #pragma unroll
    for (int j = 0; j < 8; j++) {
        float s = fmaf(buf[j], w0, fmaf(buf[j + 1], w1,
                  fmaf(buf[j + 2], w2, fmaf(buf[j + 3], w3, bias))));
        o[j] = s / (1.f + __expf(-s));
    }
    float* out = xc + ((size_t)b * DI + d) * LL + l0;
    *(float4*)&out[0] = make_float4(o[0], o[1], o[2], o[3]);
    *(float4*)&out[4] = make_float4(o[4], o[5], o[6], o[7]);
}

// ---------------------------------------------------------------------------
// x_dbl partials: part[seg][b][k][l] = sum_{d in seg(64)} xc[b][d][l]*Wx[k][d]
// ---------------------------------------------------------------------------
__global__ __launch_bounds__(256) void xproj_partial_k(const float* __restrict__ xc,
                                                       const float* __restrict__ Wx,
                                                       float* __restrict__ part) {
    const int lt = blockIdx.x;             // 0..7  (512 l each)
    const int seg = blockIdx.y;            // 0..31 (64 d each)
    const int tid = threadIdx.x;
    const int bl0 = lt * 512;
    const int b = bl0 >> 11;
    const int l = (bl0 & (LL - 1)) + tid * 2;
    const int dbase = seg * SEGW;

    __shared__ float w[SEGW][36];          // [dd][kk], row padded to 36
    for (int kk = tid >> 6; kk < KX; kk += 4)
        w[tid & 63][kk] = Wx[(size_t)kk * DI + dbase + (tid & 63)];
    __syncthreads();

    float2 acc[KX];
    #pragma unroll
    for (int kk = 0; kk < KX; kk++) acc[kk] = make_float2(0.f, 0.f);

    const float* xb = xc + ((size_t)b * DI + dbase) * LL + l;
    #pragma unroll 4
    for (int dd = 0; dd < SEGW; dd++) {
        float2 xv = *(const float2*)&xb[(size_t)dd * LL];
        #pragma unroll
        for (int q = 0; q < 8; q++) {
            float4 wv = *(const float4*)&w[dd][q * 4];
            float wa[4] = {wv.x, wv.y, wv.z, wv.w};
            #pragma unroll
            for (int t = 0; t < 4; t++) {
                acc[q * 4 + t].x = fmaf(xv.x, wa[t], acc[q * 4 + t].x);
                acc[q * 4 + t].y = fmaf(xv.y, wa[t], acc[q * 4 + t].y);
            }
        }
        float wl = w[dd][32];
        acc[32].x = fmaf(xv.x, wl, acc[32].x);
        acc[32].y = fmaf(xv.y, wl, acc[32].y);
    }
    #pragma unroll
    for (int kk = 0; kk < KX; kk++)
        *(float2*)&part[(((size_t)seg * BB + b) * KX + kk) * LL + l] = acc[kk];
}

__global__ __launch_bounds__(256) void xproj_reduce_k(const float* __restrict__ part,
                                                      float* __restrict__ xdbl) {
    const int i = blockIdx.x * 256 + threadIdx.x;    // float4 index
    if (i >= (BB * KX * LL) / 4) return;
    float4 s = make_float4(0.f, 0.f, 0.f, 0.f);
    #pragma unroll
    for (int seg = 0; seg < SEGS; seg++) {
        float4 v = *(const float4*)&part[(size_t)seg * BB * KX * LL + (size_t)i * 4];
        s.x += v.x; s.y += v.y; s.z += v.z; s.w += v.w;
    }
    *(float4*)&xdbl[(size_t)i * 4] = s;
}

// ---------------------------------------------------------------------------
// Merged local scan: thread-per-d, 16 states in regs, raw v_exp_f32.
// Writes y0 (+x*Dskip) fp32 in-place over xc, cum fp16 -> cumh,
// terminal h -> hloc, chunk dt-sum -> sumc. No cross-lane ops.
// ---------------------------------------------------------------------------
__global__ __launch_bounds__(256) void scan_local_k(float* xc,     // x in / y0 out
                                                    const float* __restrict__ xdbl,
                                                    const float* __restrict__ Alog,
                                                    const float* __restrict__ Wdt,
                                                    const float* __restrict__ bdt,
                                                    const float* __restrict__ Dskip,
                                                    float* __restrict__ hloc,
                                                    float* __restrict__ sumc,
                                                    ushort* __restrict__ cumh) {
    const int blk = blockIdx.x;            // c*16 + b*8 + dblk
    const int dblk = blk & 7;
    const int b = (blk >> 3) & 1;
    const int c = blk >> 4;
    const int tid = threadIdx.x;
    const int d = dblk * 256 + tid;

    __shared__ float Bt[LC][16], Ct[LC][16], sdtr[LC];

    float a2[16], h[16];
    #pragma unroll
    for (int n = 0; n < 16; n++) {
        a2[n] = -expf(Alog[(size_t)d * DS + n]) * 1.44269504f;
        h[n] = 0.f;
    }
    const float wdt = Wdt[d], bdtv = bdt[d], dsk = Dskip[d];

    #pragma unroll
    for (int i = tid; i < LC * 16; i += 256) {           // 2 iters
        int n = i >> 5, l = i & 31;
        Bt[l][n] = xdbl[((size_t)b * KX + 1 + n) * LL + c * LC + l];
        Ct[l][n] = xdbl[((size_t)b * KX + 17 + n) * LL + c * LC + l];
    }
    if (tid < LC) sdtr[tid] = xdbl[(size_t)b * KX * LL + c * LC + tid];
    __syncthreads();

    float cum = 0.f;
    float* xrow = xc + ((size_t)b * DI + d) * LL + c * LC;
    ushort* cumrow = cumh + ((size_t)b * DI + d) * LL + c * LC;

    for (int g = 0; g < LC; g += 16) {
        float4 x0 = *(const float4*)&xrow[g];
        float4 x1 = *(const float4*)&xrow[g + 4];
        float4 x2 = *(const float4*)&xrow[g + 8];
        float4 x3 = *(const float4*)&xrow[g + 12];
        float xr[16] = {x0.x,x0.y,x0.z,x0.w, x1.x,x1.y,x1.z,x1.w,
                        x2.x,x2.y,x2.z,x2.w, x3.x,x3.y,x3.z,x3.w};
        float cwv[16];
        #pragma unroll
        for (int j = 0; j < 16; j++) {
            const int l = g + j;
            float v = fmaf(wdt, sdtr[l], bdtv);
            float dt = fmaxf(v, 0.f) + __logf(1.f + __expf(-fabsf(v)));  // fast softplus
            cum += dt; cwv[j] = cum;
            float u = dt * xr[j];
            float4 b0 = *(const float4*)&Bt[l][0];
            float4 b1 = *(const float4*)&Bt[l][4];
            float4 b2 = *(const float4*)&Bt[l][8];
            float4 b3 = *(const float4*)&Bt[l][12];
            float4 q0 = *(const float4*)&Ct[l][0];
            float4 q1 = *(const float4*)&Ct[l][4];
            float4 q2 = *(const float4*)&Ct[l][8];
            float4 q3 = *(const float4*)&Ct[l][12];
            float bv[16] = {b0.x,b0.y,b0.z,b0.w, b1.x,b1.y,b1.z,b1.w,
                            b2.x,b2.y,b2.z,b2.w, b3.x,b3.y,b3.z,b3.w};
            float cv[16] = {q0.x,q0.y,q0.z,q0.w, q1.x,q1.y,q1.z,q1.w,
                            q2.x,q2.y,q2.z,q2.w, q3.x,q3.y,q3.z,q3.w};
            float ya = 0.f, yb = 0.f, yc = 0.f, yd = 0.f;
            #pragma unroll
            for (int n = 0; n < 4; n++) {
                h[n]      = fmaf(fexp2(a2[n]      * dt), h[n],      u * bv[n]);
                h[n + 4]  = fmaf(fexp2(a2[n + 4]  * dt), h[n + 4],  u * bv[n + 4]);
                h[n + 8]  = fmaf(fexp2(a2[n + 8]  * dt), h[n + 8],  u * bv[n + 8]);
                h[n + 12] = fmaf(fexp2(a2[n + 12] * dt), h[n + 12], u * bv[n + 12]);
                ya = fmaf(h[n],      cv[n],      ya);
                yb = fmaf(h[n + 4],  cv[n + 4],  yb);
                yc = fmaf(h[n + 8],  cv[n + 8],  yc);
                yd = fmaf(h[n + 12], cv[n + 12], yd);
            }
            xr[j] = fmaf(xr[j], dsk, (ya + yb) + (yc + yd));   // y0
        }
        *(float4*)&xrow[g]      = make_float4(xr[0],  xr[1],  xr[2],  xr[3]);
        *(float4*)&xrow[g + 4]  = make_float4(xr[4],  xr[5],  xr[6],  xr[7]);
        *(float4*)&xrow[g + 8]  = make_float4(xr[8],  xr[9],  xr[10], xr[11]);
        *(float4*)&xrow[g + 12] = make_float4(xr[12], xr[13], xr[14], xr[15]);
        *(ushort4*)&cumrow[g]      = make_ushort4(tof16(cwv[0]),  tof16(cwv[1]),  tof16(cwv[2]),  tof16(cwv[3]));
        *(ushort4*)&cumrow[g + 4]  = make_ushort4(tof16(cwv[4]),  tof16(cwv[5]),  tof16(cwv[6]),  tof16(cwv[7]));
        *(ushort4*)&cumrow[g + 8]  = make_ushort4(tof16(cwv[8]),  tof16(cwv[9]),  tof16(cwv[10]), tof16(cwv[11]));
        *(ushort4*)&cumrow[g + 12] = make_ushort4(tof16(cwv[12]), tof16(cwv[13]), tof16(cwv[14]), tof16(cwv[15]));
    }
    float* hp = &hloc[(((size_t)c * BB + b) * DI + d) * DS];
    *(float4*)&hp[0]  = make_float4(h[0],  h[1],  h[2],  h[3]);
    *(float4*)&hp[4]  = make_float4(h[4],  h[5],  h[6],  h[7]);
    *(float4*)&hp[8]  = make_float4(h[8],  h[9],  h[10], h[11]);
    *(float4*)&hp[12] = make_float4(h[12], h[13], h[14], h[15]);
    sumc[((size_t)c * BB + b) * DI + d] = cum;
}

// ---------------------------------------------------------------------------
// Combine: serial over 64 chunk boundaries, IN-PLACE (hloc becomes hin).
// ---------------------------------------------------------------------------
__global__ __launch_bounds__(256) void combine2_k(float* __restrict__ hloc,
                                                  const float* __restrict__ sumc,
                                                  const float* __restrict__ Alog) {
    const int i = blockIdx.x * 256 + threadIdx.x;   // (b*DI+d)*16+n
    const int n = i & 15;
    const int bd = i >> 4;
    const int d = bd & (DI - 1);
    const float a2 = -expf(Alog[(size_t)d * DS + n]) * 1.44269504f;
    float h = 0.f;
    for (int c = 0; c < NC; c++) {
        size_t idx = ((size_t)c * BB * DI + bd) * DS + n;
        float t = hloc[idx];
        hloc[idx] = h;                              // h entering chunk c
        float P = fexp2(a2 * sumc[(size_t)c * BB * DI + bd]);
        h = fmaf(P, h, t);
    }
}

// ---------------------------------------------------------------------------
// y fixup (fully parallel): y = (y0 + sum_n C[n,l]*exp2(a2*cum[l])*hin[n])
//                               * silu(z),  z from bf16 xzb, cum from fp16.
// Emitted transposed bf16 ybf[(b*L+l)][d].
// ---------------------------------------------------------------------------
__global__ __launch_bounds__(256) void yfix_k(const ushort* __restrict__ xzb,  // z half bf16
                                              const ushort* __restrict__ cumh, // fp16 cum
                                              const float* __restrict__ xc,    // y0
                                              const float* __restrict__ xdbl,
                                              const float* __restrict__ Alog,
                                              const float* __restrict__ hin,
                                              ushort* __restrict__ ybf) {
    const int bl0 = blockIdx.x * 64;
    const int b = bl0 >> 11, l0 = bl0 & (LL - 1);
    const int d0 = blockIdx.y * 64;
    const int tid = threadIdx.x;
    const int dl = tid & 63;
    const int lq = tid >> 6;                  // 0..3 -> 16 l's each
    const int d = d0 + dl;
    const int lbase = l0 + lq * 16;
    const int c = lbase / LC;                 // chunk of this 16-l subgroup

    __shared__ float Ctile[64][16];           // [l][n]
    __shared__ ushort sy[64][72];             // bf16 transpose tile (padded)

    {   // stage C
        int li = tid & 63, n4 = (tid >> 6) * 4;
        #pragma unroll
        for (int k = 0; k < 4; k++)
            Ctile[li][n4 + k] = xdbl[((size_t)b * KX + 17 + n4 + k) * LL + l0 + li];
    }
    float a2[16], hi[16];
    #pragma unroll
    for (int n = 0; n < 16; n++)
        a2[n] = -expf(Alog[(size_t)d * DS + n]) * 1.44269504f;
    {
        const float* hp = &hin[(((size_t)c * BB + b) * DI + d) * DS];
        float4 h0 = *(const float4*)&hp[0];
        float4 h1 = *(const float4*)&hp[4];
        float4 h2 = *(const float4*)&hp[8];
        float4 h3 = *(const float4*)&hp[12];
        hi[0]=h0.x; hi[1]=h0.y; hi[2]=h0.z; hi[3]=h0.w;
        hi[4]=h1.x; hi[5]=h1.y; hi[6]=h1.z; hi[7]=h1.w;
        hi[8]=h2.x; hi[9]=h2.y; hi[10]=h2.z; hi[11]=h2.w;
        hi[12]=h3.x; hi[13]=h3.y; hi[14]=h3.z; hi[15]=h3.w;
    }
    const ushort* cumr = cumh + ((size_t)b * DI + d) * LL + lbase;
    const float*  y0r  = xc   + ((size_t)b * DI + d) * LL + lbase;
    const ushort* zr   = xzb  + ((size_t)b * D2 + DI + d) * LL + lbase;
    ushort4 cu0 = *(const ushort4*)&cumr[0],  cu1 = *(const ushort4*)&cumr[4];
    ushort4 cu2 = *(const ushort4*)&cumr[8],  cu3 = *(const ushort4*)&cumr[12];
    float4 y0v = *(const float4*)&y0r[0],  y1v = *(const float4*)&y0r[4];
    float4 y2v = *(const float4*)&y0r[8],  y3v = *(const float4*)&y0r[12];
    ushort4 zu0 = *(const ushort4*)&zr[0], zu1 = *(const ushort4*)&zr[4];
    ushort4 zu2 = *(const ushort4*)&zr[8], zu3 = *(const ushort4*)&zr[12];
    float cm[16] = {f162f(cu0.x),f162f(cu0.y),f162f(cu0.z),f162f(cu0.w),
                    f162f(cu1.x),f162f(cu1.y),f162f(cu1.z),f162f(cu1.w),
                    f162f(cu2.x),f162f(cu2.y),f162f(cu2.z),f162f(cu2.w),
                    f162f(cu3.x),f162f(cu3.y),f162f(cu3.z),f162f(cu3.w)};
    float yv[16] = {y0v.x,y0v.y,y0v.z,y0v.w, y1v.x,y1v.y,y1v.z,y1v.w,
                    y2v.x,y2v.y,y2v.z,y2v.w, y3v.x,y3v.y,y3v.z,y3v.w};
    float zv[16] = {bf2f(zu0.x),bf2f(zu0.y),bf2f(zu0.z),bf2f(zu0.w),
                    bf2f(zu1.x),bf2f(zu1.y),bf2f(zu1.z),bf2f(zu1.w),
                    bf2f(zu2.x),bf2f(zu2.y),bf2f(zu2.z),bf2f(zu2.w),
                    bf2f(zu3.x),bf2f(zu3.y),bf2f(zu3.z),bf2f(zu3.w)};
    __syncthreads();
    #pragma unroll
    for (int j = 0; j < 16; j++) {
        int lidx = lq * 16 + j;
        float4 a0 = *(const float4*)&Ctile[lidx][0];
        float4 a1 = *(const float4*)&Ctile[lidx][4];
        float4 a2v = *(const float4*)&Ctile[lidx][8];
        float4 a3 = *(const float4*)&Ctile[lidx][12];
        float cv[16] = {a0.x,a0.y,a0.z,a0.w, a1.x,a1.y,a1.z,a1.w,
                        a2v.x,a2v.y,a2v.z,a2v.w, a3.x,a3.y,a3.z,a3.w};
        float corr = 0.f;
        #pragma unroll
        for (int n = 0; n < 16; n++)
            corr = fmaf(cv[n] * hi[n], fexp2(a2[n] * cm[j]), corr);
        float z = zv[j];
        float zs = z / (1.f + __expf(-z));
        float y = (yv[j] + corr) * zs;
        sy[lidx][dl] = tobf(y);
    }
    __syncthreads();
    {
        int lw = tid >> 2, p = tid & 3;
        uint4 v0 = *(const uint4*)&sy[lw][p * 16];
        uint4 v1 = *(const uint4*)&sy[lw][p * 16 + 8];
        ushort* orow = &ybf[((size_t)b * LL + l0 + lw) * DI + d0 + p * 16];
        *(uint4*)&orow[0] = v0;
        *(uint4*)&orow[8] = v1;
    }
}

// ---------------------------------------------------------------------------
extern "C" void kernel_launch(void* const* d_in, const int* in_sizes, int n_in,
                              void* d_out, int out_size, void* d_ws, size_t ws_size,
                              hipStream_t stream) {
    const float* hs   = (const float*)d_in[0];
    const float* Win  = (const float*)d_in[1];
    const float* cw   = (const float*)d_in[2];
    const float* cb   = (const float*)d_in[3];
    const float* Wx   = (const float*)d_in[4];
    const float* Wdt  = (const float*)d_in[5];
    const float* bdt  = (const float*)d_in[6];
    const float* Alog = (const float*)d_in[7];
    const float* Dsk  = (const float*)d_in[8];
    const float* Wout = (const float*)d_in[9];
    float* out = (float*)d_out;

    // ---- layout (float slots), total 29,757,440 f = 119.0 MB (< 126.8 proven)
    //  xzbf  [8,388,608] : bf16 xz     (gemm1 -> conv(x), yfix(z))
    //  xc    [8,388,608] : x fp32      (conv -> xproj, scan: y0 in-place -> yfix)
    //  xdbl  [  135,168] : x_dbl       (reduce -> scan/yfix)
    //  slot1 [8,650,752] : part(dead after reduce) -> hloc+sumc -> ybf@4,456,448
    //                      Woutb @0 after yfix (hloc dead)
    //  slot2 [4,194,304] : Winb+hsb (dead after gemm1) -> cumh fp16
    float* xzbf  = (float*)d_ws;
    float* xc    = xzbf  + (size_t)8388608;
    float* xdbl  = xc    + (size_t)8388608;
    float* slot1 = xdbl  + (size_t)135168;
    float* slot2 = slot1 + (size_t)8650752;

    ushort* xzb   = (ushort*)xzbf;
    float*  part  = slot1;
    float*  hloc  = slot1;
    float*  sumc  = slot1 + (size_t)4194304;
    ushort* ybf   = (ushort*)(slot1 + (size_t)4456448);
    ushort* Woutb = (ushort*)slot1;
    ushort* Winb  = (ushort*)slot2;
    ushort* hsb   = Winb + (size_t)D2 * DM;
    ushort* cumh  = (ushort*)slot2;

    cvt2_k<<<4096, 256, 0, stream>>>(Win, hs, (D2 * DM) / 8,
                                     (D2 * DM + BB * LL * DM) / 8, Winb);
    mfma_nt_k<DM, 0><<<dim3(32, 32), 256, 0, stream>>>(Winb, hsb, xzb);
    conv_silu_k<<<BB * DI, 256, 0, stream>>>(xzb, cw, cb, xc);
    xproj_partial_k<<<dim3(8, SEGS), 256, 0, stream>>>(xc, Wx, part);
    xproj_reduce_k<<<(BB * KX * LL / 4 + 255) / 256, 256, 0, stream>>>(part, xdbl);
    scan_local_k<<<NC * BB * 8, 256, 0, stream>>>(xc, xdbl, Alog, Wdt, bdt, Dsk,
                                                  hloc, sumc, cumh);
    combine2_k<<<(BB * DI * DS) / 256, 256, 0, stream>>>(hloc, sumc, Alog);
    yfix_k<<<dim3((BB * LL) / 64, DI / 64), 256, 0, stream>>>(xzb, cumh, xc, xdbl,
                                                              Alog, hloc, ybf);
    cvt_bf16_k<<<1024, 256, 0, stream>>>(Wout, Woutb, (DM * DI) / 8);
    mfma_nt_k<DI, 1><<<dim3(8, 32), 256, 0, stream>>>(ybf, Woutb, out);
}

// Round 12
// 224.451 us; speedup vs baseline: 1.2176x; 1.0188x over previous
//
#include <hip/hip_runtime.h>
#include <hip/hip_bf16.h>
#include <hip/hip_fp16.h>
#include <math.h>

#define BB 2
#define LL 2048
#define DM 1024
#define DS 16
#define DI 2048
#define KX 33          // 1 + 2*D_STATE
#define D2 (2*DI)      // 4096
#define NC 64          // scan chunks
#define LC 32          // chunk length (NC*LC == LL)
#define SEGS 32        // xproj d-segments
#define SEGW 64        // d per segment

typedef __attribute__((ext_vector_type(8))) short short8v;   // 8 bf16 (4 VGPRs)
typedef __attribute__((ext_vector_type(4))) float f32x4;

__device__ __forceinline__ void gload16(const void* g, void* l) {
    __builtin_amdgcn_global_load_lds((const __attribute__((address_space(1))) void*)g,
                                     (__attribute__((address_space(3))) void*)l,
                                     16, 0, 0);
}

__device__ __forceinline__ ushort tobf(float v) {
    __hip_bfloat16 h = __float2bfloat16(v);
    return *(ushort*)&h;
}
__device__ __forceinline__ float bf2f(ushort u) {
    return __uint_as_float((unsigned)u << 16);
}
__device__ __forceinline__ ushort tof16(float v) {
    __half h = __float2half(v);
    return *(ushort*)&h;
}
__device__ __forceinline__ float f162f(ushort u) {
    __half h = *(__half*)&u;
    return __half2float(h);
}
// raw v_exp_f32 — single instruction; inputs here are always <= 0 (safe range)
__device__ __forceinline__ float fexp2(float x) {
    return __builtin_amdgcn_exp2f(x);
}

// ---------------------------------------------------------------------------
// merged fp32 -> bf16 conversion: Win | hs -> o_ab (contiguous), Wout -> o_c
// ---------------------------------------------------------------------------
__global__ __launch_bounds__(256) void cvt3_k(const float* __restrict__ a,
                                              const float* __restrict__ b,
                                              const float* __restrict__ c,
                                              int na8, int nab8, int ntot8,
                                              ushort* __restrict__ o_ab,
                                              ushort* __restrict__ o_c) {
    int i = blockIdx.x * 256 + threadIdx.x;
    if (i >= ntot8) return;
    const float* src;
    ushort* dst;
    if (i < na8)       { src = &a[(size_t)i * 8];          dst = &o_ab[(size_t)i * 8]; }
    else if (i < nab8) { src = &b[(size_t)(i - na8) * 8];  dst = &o_ab[(size_t)i * 8]; }
    else               { src = &c[(size_t)(i - nab8) * 8]; dst = &o_c[(size_t)(i - nab8) * 8]; }
    float4 v0 = *(const float4*)&src[0];
    float4 v1 = *(const float4*)&src[4];
    float v[8] = {v0.x, v0.y, v0.z, v0.w, v1.x, v1.y, v1.z, v1.w};
    ushort u[8];
    #pragma unroll
    for (int j = 0; j < 8; j++) u[j] = tobf(v[j]);
    *(ushort4*)&dst[0] = make_ushort4(u[0], u[1], u[2], u[3]);
    *(ushort4*)&dst[4] = make_ushort4(u[4], u[5], u[6], u[7]);
}

// ---------------------------------------------------------------------------
// NT bf16 MFMA GEMM, 128x128 tile, 4 waves, 4x4 fragments, BK=32.
// LDS k-slot XOR swizzle (rule-21 both-sides involution):
//   physical slot p at row R holds logical k-chunk p ^ ((R>>1)&3).
//   - staging: global source k-offset = ((lane&3) ^ ((srow>>1)&3))*8
//   - read:    fragment kq read from slot (kq ^ ((lrow>>1)&3))
// Turns the 8-way read conflict (row stride 64B -> 2 bank-quads) into 2-way.
// MODE 0: C bf16, row=d, col=bl -> xzb[((col>>11)*D2 + row)*LL + (col&2047)]
// MODE 1: C fp32, row=bl, col=m -> out[row*DM + col]
// ---------------------------------------------------------------------------
template<int K, int MODE>
__global__ __launch_bounds__(256) void mfma_nt_k(const ushort* __restrict__ A,
                                                 const ushort* __restrict__ Bm,
                                                 void* __restrict__ Cout) {
    __shared__ ushort Als[128][32];
    __shared__ ushort Bls[128][32];
    const int n0 = blockIdx.x * 128;
    const int m0 = blockIdx.y * 128;
    const int tid = threadIdx.x;
    const int w = tid >> 6, lane = tid & 63;
    const int wr = (w >> 1) * 64, wc = (w & 1) * 64;
    const int lrow = lane & 15;
    const int kq = lane >> 4;

    const int srow = (lane >> 2);                                  // staging row (rel)
    const int skof = (((lane & 3) ^ ((srow >> 1) & 3))) * 8;       // swizzled src k-chunk
    const int rslot = (kq ^ ((lrow >> 1) & 3)) * 8;                // swizzled read slot

    f32x4 acc[4][4] = {};
    for (int k0 = 0; k0 < K; k0 += 32) {
        #pragma unroll
        for (int j = 0; j < 2; j++) {
            const int rbase = w * 32 + j * 16;                     // multiple of 16
            gload16(&A [(size_t)(m0 + rbase + srow) * K + k0 + skof], &Als[rbase][0]);
            gload16(&Bm[(size_t)(n0 + rbase + srow) * K + k0 + skof], &Bls[rbase][0]);
        }
        __syncthreads();
        short8v af[4], bf[4];
        #pragma unroll
        for (int i = 0; i < 4; i++) {
            af[i] = *(const short8v*)&Als[wr + i * 16 + lrow][rslot];
            bf[i] = *(const short8v*)&Bls[wc + i * 16 + lrow][rslot];
        }
        #pragma unroll
        for (int i = 0; i < 4; i++)
            #pragma unroll
            for (int jn = 0; jn < 4; jn++)
                acc[i][jn] = __builtin_amdgcn_mfma_f32_16x16x32_bf16(af[i], bf[jn], acc[i][jn], 0, 0, 0);
        __syncthreads();
    }
    #pragma unroll
    for (int i = 0; i < 4; i++) {
        #pragma unroll
        for (int jn = 0; jn < 4; jn++) {
            #pragma unroll
            for (int r = 0; r < 4; r++) {
                int row = m0 + wr + i * 16 + (lane >> 4) * 4 + r;
                int col = n0 + wc + jn * 16 + (lane & 15);
                if constexpr (MODE == 0) {
                    size_t off = ((size_t)(col >> 11) * D2 + row) * LL + (col & (LL - 1));
                    ((ushort*)Cout)[off] = tobf(acc[i][jn][r]);
                } else {
                    ((float*)Cout)[(size_t)row * DM + col] = acc[i][jn][r];
                }
            }
        }
    }
}

// ---------------------------------------------------------------------------
// Depthwise causal conv(4) + bias + SiLU on bf16 x-half of xzb -> xc (fp32)
// ---------------------------------------------------------------------------
__global__ __launch_bounds__(256) void conv_silu_k(const ushort* __restrict__ xzb,
                                                   const float* __restrict__ cw,
                                                   const float* __restrict__ cb,
                                                   float* __restrict__ xc) {
    const int row = blockIdx.x;             // 0..B*DI-1
    const int b = row >> 11, d = row & (DI - 1);
    const ushort* xr = xzb + ((size_t)b * D2 + d) * LL;
    float4 wv = *(const float4*)&cw[d * 4];
    const float w0 = wv.x, w1 = wv.y, w2 = wv.z, w3 = wv.w;
    const float bias = cb[d];
    const int l0 = threadIdx.x * 8;
    ushort4 pv = (l0 >= 4) ? *(const ushort4*)&xr[l0 - 4]
                           : make_ushort4(0, 0, 0, 0);
    ushort4 c0 = *(const ushort4*)&xr[l0];
    ushort4 c1 = *(const ushort4*)&xr[l0 + 4];
    float buf[11] = {bf2f(pv.y), bf2f(pv.z), bf2f(pv.w),
                     bf2f(c0.x), bf2f(c0.y), bf2f(c0.z), bf2f(c0.w),
                     bf2f(c1.x), bf2f(c1.y), bf2f(c1.z), bf2f(c1.w)};
    float o[8];
    #pragma unroll
    for (int j = 0; j < 8; j++) {
        float s = fmaf(buf[j], w0, fmaf(buf[j + 1], w1,
                  fmaf(buf[j + 2], w2, fmaf(buf[j + 3], w3, bias))));
        o[j] = s / (1.f + __expf(-s));
    }
    float* out = xc + ((size_t)b * DI + d) * LL + l0;
    *(float4*)&out[0] = make_float4(o[0], o[1], o[2], o[3]);
    *(float4*)&out[4] = make_float4(o[4], o[5], o[6], o[7]);
}

// ---------------------------------------------------------------------------
// x_dbl partials: part[seg][b][k][l] = sum_{d in seg(64)} xc[b][d][l]*Wx[k][d]
// ---------------------------------------------------------------------------
__global__ __launch_bounds__(256) void xproj_partial_k(const float* __restrict__ xc,
                                                       const float* __restrict__ Wx,
                                                       float* __restrict__ part) {
    const int lt = blockIdx.x;             // 0..7  (512 l each)
    const int seg = blockIdx.y;            // 0..31 (64 d each)
    const int tid = threadIdx.x;
    const int bl0 = lt * 512;
    const int b = bl0 >> 11;
    const int l = (bl0 & (LL - 1)) + tid * 2;
    const int dbase = seg * SEGW;

    __shared__ float w[SEGW][36];          // [dd][kk], row padded to 36
    for (int kk = tid >> 6; kk < KX; kk += 4)
        w[tid & 63][kk] = Wx[(size_t)kk * DI + dbase + (tid & 63)];
    __syncthreads();

    float2 acc[KX];
    #pragma unroll
    for (int kk = 0; kk < KX; kk++) acc[kk] = make_float2(0.f, 0.f);

    const float* xb = xc + ((size_t)b * DI + dbase) * LL + l;
    #pragma unroll 4
    for (int dd = 0; dd < SEGW; dd++) {
        float2 xv = *(const float2*)&xb[(size_t)dd * LL];
        #pragma unroll
        for (int q = 0; q < 8; q++) {
            float4 wv = *(const float4*)&w[dd][q * 4];
            float wa[4] = {wv.x, wv.y, wv.z, wv.w};
            #pragma unroll
            for (int t = 0; t < 4; t++) {
                acc[q * 4 + t].x = fmaf(xv.x, wa[t], acc[q * 4 + t].x);
                acc[q * 4 + t].y = fmaf(xv.y, wa[t], acc[q * 4 + t].y);
            }
        }
        float wl = w[dd][32];
        acc[32].x = fmaf(xv.x, wl, acc[32].x);
        acc[32].y = fmaf(xv.y, wl, acc[32].y);
    }
    #pragma unroll
    for (int kk = 0; kk < KX; kk++)
        *(float2*)&part[(((size_t)seg * BB + b) * KX + kk) * LL + l] = acc[kk];
}

__global__ __launch_bounds__(256) void xproj_reduce_k(const float* __restrict__ part,
                                                      float* __restrict__ xdbl) {
    const int i = blockIdx.x * 256 + threadIdx.x;    // float4 index
    if (i >= (BB * KX * LL) / 4) return;
    float4 s = make_float4(0.f, 0.f, 0.f, 0.f);
    #pragma unroll
    for (int seg = 0; seg < SEGS; seg++) {
        float4 v = *(const float4*)&part[(size_t)seg * BB * KX * LL + (size_t)i * 4];
        s.x += v.x; s.y += v.y; s.z += v.z; s.w += v.w;
    }
    *(float4*)&xdbl[(size_t)i * 4] = s;
}

// ---------------------------------------------------------------------------
// Merged local scan: thread-per-d, 16 states in regs, raw v_exp_f32.
// Writes y0 (+x*Dskip) fp32 in-place over xc, cum fp16 -> cumh,
// terminal h -> hloc, chunk dt-sum -> sumc. No cross-lane ops.
// ---------------------------------------------------------------------------
__global__ __launch_bounds__(256) void scan_local_k(float* xc,     // x in / y0 out
                                                    const float* __restrict__ xdbl,
                                                    const float* __restrict__ Alog,
                                                    const float* __restrict__ Wdt,
                                                    const float* __restrict__ bdt,
                                                    const float* __restrict__ Dskip,
                                                    float* __restrict__ hloc,
                                                    float* __restrict__ sumc,
                                                    ushort* __restrict__ cumh) {
    const int blk = blockIdx.x;            // c*16 + b*8 + dblk
    const int dblk = blk & 7;
    const int b = (blk >> 3) & 1;
    const int c = blk >> 4;
    const int tid = threadIdx.x;
    const int d = dblk * 256 + tid;

    __shared__ float Bt[LC][16], Ct[LC][16], sdtr[LC];

    float a2[16], h[16];
    #pragma unroll
    for (int n = 0; n < 16; n++) {
        a2[n] = -expf(Alog[(size_t)d * DS + n]) * 1.44269504f;
        h[n] = 0.f;
    }
    const float wdt = Wdt[d], bdtv = bdt[d], dsk = Dskip[d];

    #pragma unroll
    for (int i = tid; i < LC * 16; i += 256) {           // 2 iters
        int n = i >> 5, l = i & 31;
        Bt[l][n] = xdbl[((size_t)b * KX + 1 + n) * LL + c * LC + l];
        Ct[l][n] = xdbl[((size_t)b * KX + 17 + n) * LL + c * LC + l];
    }
    if (tid < LC) sdtr[tid] = xdbl[(size_t)b * KX * LL + c * LC + tid];
    __syncthreads();

    float cum = 0.f;
    float* xrow = xc + ((size_t)b * DI + d) * LL + c * LC;
    ushort* cumrow = cumh + ((size_t)b * DI + d) * LL + c * LC;

    for (int g = 0; g < LC; g += 16) {
        float4 x0 = *(const float4*)&xrow[g];
        float4 x1 = *(const float4*)&xrow[g + 4];
        float4 x2 = *(const float4*)&xrow[g + 8];
        float4 x3 = *(const float4*)&xrow[g + 12];
        float xr[16] = {x0.x,x0.y,x0.z,x0.w, x1.x,x1.y,x1.z,x1.w,
                        x2.x,x2.y,x2.z,x2.w, x3.x,x3.y,x3.z,x3.w};
        float cwv[16];
        #pragma unroll
        for (int j = 0; j < 16; j++) {
            const int l = g + j;
            float v = fmaf(wdt, sdtr[l], bdtv);
            float dt = fmaxf(v, 0.f) + __logf(1.f + __expf(-fabsf(v)));  // fast softplus
            cum += dt; cwv[j] = cum;
            float u = dt * xr[j];
            float4 b0 = *(const float4*)&Bt[l][0];
            float4 b1 = *(const float4*)&Bt[l][4];
            float4 b2 = *(const float4*)&Bt[l][8];
            float4 b3 = *(const float4*)&Bt[l][12];
            float4 q0 = *(const float4*)&Ct[l][0];
            float4 q1 = *(const float4*)&Ct[l][4];
            float4 q2 = *(const float4*)&Ct[l][8];
            float4 q3 = *(const float4*)&Ct[l][12];
            float bv[16] = {b0.x,b0.y,b0.z,b0.w, b1.x,b1.y,b1.z,b1.w,
                            b2.x,b2.y,b2.z,b2.w, b3.x,b3.y,b3.z,b3.w};
            float cv[16] = {q0.x,q0.y,q0.z,q0.w, q1.x,q1.y,q1.z,q1.w,
                            q2.x,q2.y,q2.z,q2.w, q3.x,q3.y,q3.z,q3.w};
            float ya = 0.f, yb = 0.f, yc = 0.f, yd = 0.f;
            #pragma unroll
            for (int n = 0; n < 4; n++) {
                h[n]      = fmaf(fexp2(a2[n]      * dt), h[n],      u * bv[n]);
                h[n + 4]  = fmaf(fexp2(a2[n + 4]  * dt), h[n + 4],  u * bv[n + 4]);
                h[n + 8]  = fmaf(fexp2(a2[n + 8]  * dt), h[n + 8],  u * bv[n + 8]);
                h[n + 12] = fmaf(fexp2(a2[n + 12] * dt), h[n + 12], u * bv[n + 12]);
                ya = fmaf(h[n],      cv[n],      ya);
                yb = fmaf(h[n + 4],  cv[n + 4],  yb);
                yc = fmaf(h[n + 8],  cv[n + 8],  yc);
                yd = fmaf(h[n + 12], cv[n + 12], yd);
            }
            xr[j] = fmaf(xr[j], dsk, (ya + yb) + (yc + yd));   // y0
        }
        *(float4*)&xrow[g]      = make_float4(xr[0],  xr[1],  xr[2],  xr[3]);
        *(float4*)&xrow[g + 4]  = make_float4(xr[4],  xr[5],  xr[6],  xr[7]);
        *(float4*)&xrow[g + 8]  = make_float4(xr[8],  xr[9],  xr[10], xr[11]);
        *(float4*)&xrow[g + 12] = make_float4(xr[12], xr[13], xr[14], xr[15]);
        *(ushort4*)&cumrow[g]      = make_ushort4(tof16(cwv[0]),  tof16(cwv[1]),  tof16(cwv[2]),  tof16(cwv[3]));
        *(ushort4*)&cumrow[g + 4]  = make_ushort4(tof16(cwv[4]),  tof16(cwv[5]),  tof16(cwv[6]),  tof16(cwv[7]));
        *(ushort4*)&cumrow[g + 8]  = make_ushort4(tof16(cwv[8]),  tof16(cwv[9]),  tof16(cwv[10]), tof16(cwv[11]));
        *(ushort4*)&cumrow[g + 12] = make_ushort4(tof16(cwv[12]), tof16(cwv[13]), tof16(cwv[14]), tof16(cwv[15]));
    }
    float* hp = &hloc[(((size_t)c * BB + b) * DI + d) * DS];
    *(float4*)&hp[0]  = make_float4(h[0],  h[1],  h[2],  h[3]);
    *(float4*)&hp[4]  = make_float4(h[4],  h[5],  h[6],  h[7]);
    *(float4*)&hp[8]  = make_float4(h[8],  h[9],  h[10], h[11]);
    *(float4*)&hp[12] = make_float4(h[12], h[13], h[14], h[15]);
    sumc[((size_t)c * BB + b) * DI + d] = cum;
}

// ---------------------------------------------------------------------------
// Combine: serial over 64 chunk boundaries, IN-PLACE (hloc becomes hin).
// ---------------------------------------------------------------------------
__global__ __launch_bounds__(256) void combine2_k(float* __restrict__ hloc,
                                                  const float* __restrict__ sumc,
                                                  const float* __restrict__ Alog) {
    const int i = blockIdx.x * 256 + threadIdx.x;   // (b*DI+d)*16+n
    const int n = i & 15;
    const int bd = i >> 4;
    const int d = bd & (DI - 1);
    const float a2 = -expf(Alog[(size_t)d * DS + n]) * 1.44269504f;
    float h = 0.f;
    for (int c = 0; c < NC; c++) {
        size_t idx = ((size_t)c * BB * DI + bd) * DS + n;
        float t = hloc[idx];
        hloc[idx] = h;                              // h entering chunk c
        float P = fexp2(a2 * sumc[(size_t)c * BB * DI + bd]);
        h = fmaf(P, h, t);
    }
}

// ---------------------------------------------------------------------------
// y fixup (fully parallel): y = (y0 + sum_n C[n,l]*exp2(a2*cum[l])*hin[n])
//                               * silu(z),  z from bf16 xzb, cum from fp16.
// Emitted transposed bf16 ybf[(b*L+l)][d].
// ---------------------------------------------------------------------------
__global__ __launch_bounds__(256) void yfix_k(const ushort* __restrict__ xzb,  // z half bf16
                                              const ushort* __restrict__ cumh, // fp16 cum
                                              const float* __restrict__ xc,    // y0
                                              const float* __restrict__ xdbl,
                                              const float* __restrict__ Alog,
                                              const float* __restrict__ hin,
                                              ushort* __restrict__ ybf) {
    const int bl0 = blockIdx.x * 64;
    const int b = bl0 >> 11, l0 = bl0 & (LL - 1);
    const int d0 = blockIdx.y * 64;
    const int tid = threadIdx.x;
    const int dl = tid & 63;
    const int lq = tid >> 6;                  // 0..3 -> 16 l's each
    const int d = d0 + dl;
    const int lbase = l0 + lq * 16;
    const int c = lbase / LC;                 // chunk of this 16-l subgroup

    __shared__ float Ctile[64][16];           // [l][n]
    __shared__ ushort sy[64][72];             // bf16 transpose tile (padded)

    {   // stage C
        int li = tid & 63, n4 = (tid >> 6) * 4;
        #pragma unroll
        for (int k = 0; k < 4; k++)
            Ctile[li][n4 + k] = xdbl[((size_t)b * KX + 17 + n4 + k) * LL + l0 + li];
    }
    float a2[16], hi[16];
    #pragma unroll
    for (int n = 0; n < 16; n++)
        a2[n] = -expf(Alog[(size_t)d * DS + n]) * 1.44269504f;
    {
        const float* hp = &hin[(((size_t)c * BB + b) * DI + d) * DS];
        float4 h0 = *(const float4*)&hp[0];
        float4 h1 = *(const float4*)&hp[4];
        float4 h2 = *(const float4*)&hp[8];
        float4 h3 = *(const float4*)&hp[12];
        hi[0]=h0.x; hi[1]=h0.y; hi[2]=h0.z; hi[3]=h0.w;
        hi[4]=h1.x; hi[5]=h1.y; hi[6]=h1.z; hi[7]=h1.w;
        hi[8]=h2.x; hi[9]=h2.y; hi[10]=h2.z; hi[11]=h2.w;
        hi[12]=h3.x; hi[13]=h3.y; hi[14]=h3.z; hi[15]=h3.w;
    }
    const ushort* cumr = cumh + ((size_t)b * DI + d) * LL + lbase;
    const float*  y0r  = xc   + ((size_t)b * DI + d) * LL + lbase;
    const ushort* zr   = xzb  + ((size_t)b * D2 + DI + d) * LL + lbase;
    ushort4 cu0 = *(const ushort4*)&cumr[0],  cu1 = *(const ushort4*)&cumr[4];
    ushort4 cu2 = *(const ushort4*)&cumr[8],  cu3 = *(const ushort4*)&cumr[12];
    float4 y0v = *(const float4*)&y0r[0],  y1v = *(const float4*)&y0r[4];
    float4 y2v = *(const float4*)&y0r[8],  y3v = *(const float4*)&y0r[12];
    ushort4 zu0 = *(const ushort4*)&zr[0], zu1 = *(const ushort4*)&zr[4];
    ushort4 zu2 = *(const ushort4*)&zr[8], zu3 = *(const ushort4*)&zr[12];
    float cm[16] = {f162f(cu0.x),f162f(cu0.y),f162f(cu0.z),f162f(cu0.w),
                    f162f(cu1.x),f162f(cu1.y),f162f(cu1.z),f162f(cu1.w),
                    f162f(cu2.x),f162f(cu2.y),f162f(cu2.z),f162f(cu2.w),
                    f162f(cu3.x),f162f(cu3.y),f162f(cu3.z),f162f(cu3.w)};
    float yv[16] = {y0v.x,y0v.y,y0v.z,y0v.w, y1v.x,y1v.y,y1v.z,y1v.w,
                    y2v.x,y2v.y,y2v.z,y2v.w, y3v.x,y3v.y,y3v.z,y3v.w};
    float zv[16] = {bf2f(zu0.x),bf2f(zu0.y),bf2f(zu0.z),bf2f(zu0.w),
                    bf2f(zu1.x),bf2f(zu1.y),bf2f(zu1.z),bf2f(zu1.w),
                    bf2f(zu2.x),bf2f(zu2.y),bf2f(zu2.z),bf2f(zu2.w),
                    bf2f(zu3.x),bf2f(zu3.y),bf2f(zu3.z),bf2f(zu3.w)};
    __syncthreads();
    #pragma unroll
    for (int j = 0; j < 16; j++) {
        int lidx = lq * 16 + j;
        float4 a0 = *(const float4*)&Ctile[lidx][0];
        float4 a1 = *(const float4*)&Ctile[lidx][4];
        float4 a2v = *(const float4*)&Ctile[lidx][8];
        float4 a3 = *(const float4*)&Ctile[lidx][12];
        float cv[16] = {a0.x,a0.y,a0.z,a0.w, a1.x,a1.y,a1.z,a1.w,
                        a2v.x,a2v.y,a2v.z,a2v.w, a3.x,a3.y,a3.z,a3.w};
        float corr = 0.f;
        #pragma unroll
        for (int n = 0; n < 16; n++)
            corr = fmaf(cv[n] * hi[n], fexp2(a2[n] * cm[j]), corr);
        float z = zv[j];
        float zs = z / (1.f + __expf(-z));
        float y = (yv[j] + corr) * zs;
        sy[lidx][dl] = tobf(y);
    }
    __syncthreads();
    {
        int lw = tid >> 2, p = tid & 3;
        uint4 v0 = *(const uint4*)&sy[lw][p * 16];
        uint4 v1 = *(const uint4*)&sy[lw][p * 16 + 8];
        ushort* orow = &ybf[((size_t)b * LL + l0 + lw) * DI + d0 + p * 16];
        *(uint4*)&orow[0] = v0;
        *(uint4*)&orow[8] = v1;
    }
}

// ---------------------------------------------------------------------------
extern "C" void kernel_launch(void* const* d_in, const int* in_sizes, int n_in,
                              void* d_out, int out_size, void* d_ws, size_t ws_size,
                              hipStream_t stream) {
    const float* hs   = (const float*)d_in[0];
    const float* Win  = (const float*)d_in[1];
    const float* cw   = (const float*)d_in[2];
    const float* cb   = (const float*)d_in[3];
    const float* Wx   = (const float*)d_in[4];
    const float* Wdt  = (const float*)d_in[5];
    const float* bdt  = (const float*)d_in[6];
    const float* Alog = (const float*)d_in[7];
    const float* Dsk  = (const float*)d_in[8];
    const float* Wout = (const float*)d_in[9];
    float* out = (float*)d_out;

    // ---- layout (float slots), total 30,806,016 f = 123.2 MB (< 126.4 proven)
    //  xzbf  [8,388,608] : bf16 xz     (gemm1 -> conv(x), yfix(z))
    //  xc    [8,388,608] : x fp32      (conv -> xproj, scan: y0 in-place -> yfix)
    //  xdbl  [  135,168] : x_dbl       (reduce -> scan/yfix)
    //  slot1 [8,650,752] : part(dead after reduce) -> hloc+sumc -> ybf@4,456,448
    //  slot2 [4,194,304] : Winb+hsb (dead after gemm1) -> cumh fp16
    //  wob   [1,048,576] : Woutb bf16 (cvt3 -> gemm2, persistent)
    float* xzbf  = (float*)d_ws;
    float* xc    = xzbf  + (size_t)8388608;
    float* xdbl  = xc    + (size_t)8388608;
    float* slot1 = xdbl  + (size_t)135168;
    float* slot2 = slot1 + (size_t)8650752;
    float* wob   = slot2 + (size_t)4194304;

    ushort* xzb   = (ushort*)xzbf;
    float*  part  = slot1;
    float*  hloc  = slot1;
    float*  sumc  = slot1 + (size_t)4194304;
    ushort* ybf   = (ushort*)(slot1 + (size_t)4456448);
    ushort* Winb  = (ushort*)slot2;
    ushort* hsb   = Winb + (size_t)D2 * DM;
    ushort* cumh  = (ushort*)slot2;
    ushort* Woutb = (ushort*)wob;

    const int na8   = (D2 * DM) / 8;                   // Win
    const int nab8  = na8 + (BB * LL * DM) / 8;        // + hs
    const int ntot8 = nab8 + (DM * DI) / 8;            // + Wout
    cvt3_k<<<(ntot8 + 255) / 256, 256, 0, stream>>>(Win, hs, Wout,
                                                    na8, nab8, ntot8, Winb, Woutb);
    mfma_nt_k<DM, 0><<<dim3(32, 32), 256, 0, stream>>>(Winb, hsb, xzb);
    conv_silu_k<<<BB * DI, 256, 0, stream>>>(xzb, cw, cb, xc);
    xproj_partial_k<<<dim3(8, SEGS), 256, 0, stream>>>(xc, Wx, part);
    xproj_reduce_k<<<(BB * KX * LL / 4 + 255) / 256, 256, 0, stream>>>(part, xdbl);
    scan_local_k<<<NC * BB * 8, 256, 0, stream>>>(xc, xdbl, Alog, Wdt, bdt, Dsk,
                                                  hloc, sumc, cumh);
    combine2_k<<<(BB * DI * DS) / 256, 256, 0, stream>>>(hloc, sumc, Alog);
    yfix_k<<<dim3((BB * LL) / 64, DI / 64), 256, 0, stream>>>(xzb, cumh, xc, xdbl,
                                                              Alog, hloc, ybf);
    mfma_nt_k<DI, 1><<<dim3(8, 32), 256, 0, stream>>>(ybf, Woutb, out);
}